// Round 5
// baseline (302.035 us; speedup 1.0000x reference)
//
#include <hip/hip_runtime.h>
#include <cstdint>
#include <cstddef>

typedef _Float16 f16x8 __attribute__((ext_vector_type(8)));
typedef _Float16 f16x4 __attribute__((ext_vector_type(4)));
typedef float f32x4 __attribute__((ext_vector_type(4)));

static __device__ __forceinline__ float elu_f(float t) {
    return t > 0.0f ? t : expm1f(t);
}

// async global->LDS 16B copy: per-lane GLOBAL source, linear LDS dest
// (wave-uniform base + lane*16).
typedef __attribute__((address_space(1))) const unsigned int guint;
typedef __attribute__((address_space(3))) unsigned int       luint;
static __device__ __forceinline__ void gload_lds16(const void* g, void* l)
{
    __builtin_amdgcn_global_load_lds((guint*)g, (luint*)l, 16, 0, 0);
}

// counted vmcnt wait (T4): literal immediates only, fenced per rule #18.
template<int N>
static __device__ __forceinline__ void vm_wait()
{
    static_assert(N == 0 || N == 4 || N == 5, "vmcnt literal");
    if constexpr (N == 0)      asm volatile("s_waitcnt vmcnt(0)" ::: "memory");
    else if constexpr (N == 4) asm volatile("s_waitcnt vmcnt(4)" ::: "memory");
    else                       asm volatile("s_waitcnt vmcnt(5)" ::: "memory");
    __builtin_amdgcn_sched_barrier(0);
}

// XCD-aware block -> pooled-vertex-tile remap (XCD = bid & 7 round-robin).
static __device__ __forceinline__ int block_pu0(int bid, int P, int vshift_out, int nbl)
{
    if (nbl < 0) return bid * P;
    int xcd  = bid & 7;
    int slot = bid >> 3;
    int nb   = slot & ((1 << nbl) - 1);
    int tile = slot >> nbl;
    return ((xcd + (nb << 3)) << vshift_out) + tile * P;
}

// ---------------- weight prep: fp32 [K][C_OUT] -> fp16 tiled [y][t][kc][n][8] ----------------
template<int KTOT, int C_OUT, int BN>
__global__ __launch_bounds__(256)
void prep_w(const float* __restrict__ W, _Float16* __restrict__ o)
{
    constexpr int KT = KTOT/64;
    int i = blockIdx.x * 256 + threadIdx.x;
    if (i >= KTOT*C_OUT) return;
    int j = i & 7;
    int rest = i >> 3;
    int n = rest % BN;
    int kc = (rest / BN) & 7;
    int t = (rest / (BN*8)) % KT;
    int y = rest / (BN*8*KT);
    int k = t*64 + kc*8 + j;
    o[i] = (_Float16)W[(size_t)k*C_OUT + y*BN + n];
}

// Level-0 weights: (36,32) -> padded K=64, k = s*4 + c layout, tile [kc][n][8]
__global__ __launch_bounds__(256)
void prep_w0(const float* __restrict__ W, _Float16* __restrict__ o)
{
    int i = blockIdx.x * 256 + threadIdx.x;
    if (i >= 2048) return;
    int j = i & 7;
    int n = (i >> 3) & 31;
    int kc = i >> 8;
    int k = kc*8 + j;
    int s = k >> 2, c = k & 3;
    float v = (s < 12 && c < 3) ? W[(size_t)(s*3 + c)*32 + n] : 0.0f;
    o[i] = (_Float16)v;
}

// ---------------- x transpose: (16,32768,3) fp32 -> (32768,16,4) fp16 ----------------
__global__ __launch_bounds__(256)
void prep_xT(const float* __restrict__ x, _Float16* __restrict__ xT)
{
    __shared__ _Float16 t[16][64*4 + 8];
    const int v0 = blockIdx.x * 64;
    const int tid = threadIdx.x;
    #pragma unroll
    for (int it = 0; it < 4; ++it) {
        int e = it*256 + tid;          // 16 b x 64 v
        int b = e >> 6, v = e & 63;
        const float* p = x + ((size_t)b*32768 + v0 + v)*3;
        f16x4 h;
        h[0] = (_Float16)p[0]; h[1] = (_Float16)p[1];
        h[2] = (_Float16)p[2]; h[3] = (_Float16)0.f;
        *(f16x4*)&t[b][v*4] = h;
    }
    __syncthreads();
    #pragma unroll
    for (int it = 0; it < 2; ++it) {
        int e = it*256 + tid;          // 64 v x 8 s
        int vl = e >> 3, s = e & 7;
        f16x4 a = *(const f16x4*)&t[2*s][vl*4];
        f16x4 b = *(const f16x4*)&t[2*s+1][vl*4];
        f16x8 h;
        h[0]=a[0]; h[1]=a[1]; h[2]=a[2]; h[3]=a[3];
        h[4]=b[0]; h[5]=b[1]; h[6]=b[2]; h[7]=b[3];
        *(f16x8*)&xT[((size_t)(v0+vl)*16 + s*2)*4] = h;
    }
}

// ---------------- index pre-compose: didx0 o spiral0 -> u16-pair table ----------------
__global__ __launch_bounds__(256)
void prep_gidx(const int* __restrict__ didx, const int* __restrict__ spiral,
               unsigned int* __restrict__ g)
{
    int i = blockIdx.x*256 + threadIdx.x;   // 24576 rows x 8
    if (i >= 24576*8) return;
    int q = i & 7;
    int row = i >> 3;
    unsigned int val = 0;
    if (q < 6) {
        int v = didx[row];
        unsigned int s0 = (unsigned int)spiral[v*12 + q*2];
        unsigned int s1 = (unsigned int)spiral[v*12 + q*2 + 1];
        val = s0 | (s1 << 16);
    }
    g[i] = val;
}

// ---------------- conv0+pool0, batched-M over 16 batches ----------------
__global__ __launch_bounds__(256)
void conv0T(const _Float16* __restrict__ xT, const unsigned int* __restrict__ gidx,
            const _Float16* __restrict__ Wp, const float* __restrict__ bias,
            const float* __restrict__ dwt, _Float16* __restrict__ out)
{
    __shared__ _Float16 Ep[4][512];        // per-wave 1 KB transpose buffer
    const int tid  = threadIdx.x;
    const int wave = tid >> 6;
    const int lane = tid & 63;
    const int quad = lane >> 4;
    const int l16  = lane & 15;
    const int u0   = blockIdx.x * 8 + wave * 2;   // 2 u per wave

    f16x8 bf[2][2];
    #pragma unroll
    for (int kt = 0; kt < 2; ++kt)
        #pragma unroll
        for (int nt = 0; nt < 2; ++nt)
            bf[kt][nt] = *(const f16x8*)&Wp[(((kt*4+quad)*32) + nt*16 + l16)*8];
    float bv[2] = { bias[l16], bias[16 + l16] };

    #pragma unroll
    for (int ui = 0; ui < 2; ++ui) {
        int u = u0 + ui;
        f32x4 pacc[2] = {{0.f,0.f,0.f,0.f},{0.f,0.f,0.f,0.f}};
        #pragma unroll
        for (int kp = 0; kp < 3; ++kp) {
            int r = u*3 + kp;
            unsigned int gp0 = gidx[r*8 + quad];
            unsigned int gp1 = gidx[r*8 + 4 + quad];
            f16x4 a0 = *(const f16x4*)&xT[(size_t)(gp0 & 0xffffu)*64 + l16*4];
            f16x4 a1 = *(const f16x4*)&xT[(size_t)(gp0 >> 16)*64 + l16*4];
            f16x4 a2 = *(const f16x4*)&xT[(size_t)(gp1 & 0xffffu)*64 + l16*4];
            f16x4 a3 = *(const f16x4*)&xT[(size_t)(gp1 >> 16)*64 + l16*4];
            f16x8 af0, af1;
            af0[0]=a0[0]; af0[1]=a0[1]; af0[2]=a0[2]; af0[3]=a0[3];
            af0[4]=a1[0]; af0[5]=a1[1]; af0[6]=a1[2]; af0[7]=a1[3];
            af1[0]=a2[0]; af1[1]=a2[1]; af1[2]=a2[2]; af1[3]=a2[3];
            af1[4]=a3[0]; af1[5]=a3[1]; af1[6]=a3[2]; af1[7]=a3[3];
            float dw = dwt[r];
            #pragma unroll
            for (int nt = 0; nt < 2; ++nt) {
                f32x4 m = {0.f,0.f,0.f,0.f};
                m = __builtin_amdgcn_mfma_f32_16x16x32_f16(af0, bf[0][nt], m, 0,0,0);
                m = __builtin_amdgcn_mfma_f32_16x16x32_f16(af1, bf[1][nt], m, 0,0,0);
                #pragma unroll
                for (int rr = 0; rr < 4; ++rr)
                    pacc[nt][rr] += dw * elu_f(m[rr] + bv[nt]);
            }
        }
        #pragma unroll
        for (int nt = 0; nt < 2; ++nt)
            #pragma unroll
            for (int rr = 0; rr < 4; ++rr)
                Ep[wave][(quad*4+rr)*32 + nt*16 + l16] = (_Float16)pacc[nt][rr];
        int b  = lane >> 2;
        int c8 = lane & 3;
        f16x8 rowv = *(const f16x8*)&Ep[wave][b*32 + c8*8];
        *(f16x8*)&out[(size_t)b*262144 + (size_t)u*32 + c8*8] = rowv;
    }
}

// ---------------- fused conv+pool: 3-buffer LDS staging, COUNTED vmcnt ----------------
// Round-4 post-mortem: LDS staging won (L3 46->~20us) but each group still ate a
// full gather latency because __syncthreads drains vmcnt(0) -- including the
// loads staged a moment earlier. Round-5 applies T3+T4: three staging buffers,
// raw s_barrier, and a COUNTED s_waitcnt vmcnt(LPW) so only the stage issued
// TWO groups ago must have landed; stages g+1 and g+2 stay in flight across
// barriers. lgkmcnt(0)+barrier at group bottom makes the 3-ahead overwrite
// safe. Ledger is valid because the K-loop contains no other VMEM ops (older
// pre-loop loads retire first and cannot break the "<=LPW outstanding => stage
// g retired" guarantee). MFMA order per K-step unchanged -> identical numerics.
template<int C_IN, int C_OUT, int P, int BN, int WGM, int WGN, bool OUT_HALF>
__global__ __launch_bounds__(256)
void conv_pool_mfma(const _Float16* __restrict__ x, const int* __restrict__ spiral,
                    const _Float16* __restrict__ Wp, const float* __restrict__ bias,
                    const int* __restrict__ didx, const float* __restrict__ dwt,
                    void* __restrict__ outv, int vshift_in, int vshift_out, int nbl)
{
    constexpr int R    = 3*P;
    constexpr int KTOT = 12*C_IN;
    constexpr int KT   = KTOT/64;
    constexpr int NST  = KT*2;           // number of K=32 steps
    constexpr int WTM  = R/WGM;
    constexpr int WTN  = BN/WGN;
    constexpr int NMT  = WTM/16;
    constexpr int NNT  = WTN/16;
    constexpr int C4   = BN/4;
    constexpr int GS   = (C_IN == 32) ? 1 : 2;   // K-steps per staging group
    constexpr int NG   = NST / GS;
    constexpr int CPR  = GS * 4;         // 16B chunks per staged row-part (4 or 8)
    constexpr int CPRS = (CPR == 4) ? 2 : 3;
    constexpr int ACH  = R * CPR;        // A chunks per group
    constexpr int BCH  = GS * BN * 4;    // B chunks per group
    constexpr int AIPW = ACH / 256;      // global_load_lds instrs per wave
    constexpr int BIPW = BCH / 256;
    constexpr int LPW  = AIPW + BIPW;    // own loads per stage (vmcnt unit)
    constexpr int NBUF = 3;
    constexpr int ASUBH = R * GS * 32;   // halfs per A sub-buffer
    constexpr int BSUBH = GS * 32 * BN;  // halfs per B sub-buffer
    static_assert(WTM % 16 == 0 && WTN % 16 == 0, "tile");
    static_assert(R <= 256 && (P*C4) % 256 == 0, "loops");
    static_assert(ACH % 256 == 0 && BCH % 256 == 0, "stage");
    static_assert(NST % GS == 0 && GS*32 <= C_IN, "group");
    static_assert(NG >= 3, "pipeline depth");

    constexpr size_t BUFB = (size_t)(NBUF*(ASUBH + BSUBH)) * 2;
    constexpr size_t EB   = (size_t)R * (BN + 4) * 2;
    constexpr size_t GOFF = (BUFB > EB ? BUFB : EB);
    static_assert(GOFF + (size_t)R*12*2 <= 65536, "LDS budget");
    __shared__ __align__(16) char smem[GOFF + (size_t)R*12*2];
    _Float16* Ab = (_Float16*)smem;
    _Float16* Bb = (_Float16*)(smem + (size_t)NBUF*ASUBH*2);
    unsigned short* gidx = (unsigned short*)(smem + GOFF);
    _Float16* E = (_Float16*)smem;       // overlays staging bufs (dead after K-loop)

    const int tid  = threadIdx.x;
    const int wave = tid >> 6;
    const int lane = tid & 63;
    const int quad = lane >> 4;
    const int l16  = lane & 15;
    const int wm   = wave / WGN;
    const int wn   = wave % WGN;
    const int pu0  = block_pu0(blockIdx.x, P, vshift_out, nbl);
    const int n0   = blockIdx.y * BN;
    const int vmask_out = (1 << vshift_out) - 1;
    const int base_in = (pu0 >> vshift_out) << vshift_in;

    if (tid < R) {
        int ul = tid / 3;
        int kp = tid - ul*3;
        int u  = (pu0 + ul) & vmask_out;
        int v  = didx[u*3 + kp];
        const int* svp = spiral + v*12;
        #pragma unroll
        for (int j = 0; j < 12; ++j) gidx[tid*12 + j] = (unsigned short)svp[j];
    }
    __syncthreads();

    f32x4 acc[NMT][NNT];
    #pragma unroll
    for (int i = 0; i < NMT; ++i)
        #pragma unroll
        for (int j = 0; j < NNT; ++j) acc[i][j] = (f32x4){0.f, 0.f, 0.f, 0.f};

    const _Float16* xb = x + (size_t)base_in * C_IN;

    // chunk swizzle: slot q of row r holds global chunk q ^ SWZ(r)
    auto SWZ = [](int r) -> int {
        return (CPR == 4) ? ((r & 3) ^ ((r >> 2) & 3)) : (r & 7);
    };

    auto stage = [&](int g, int buf) {
        const int k0g = g * GS * 32;
        const int sv  = k0g / C_IN;
        const int c0  = k0g % C_IN;                  // halfs
        _Float16* Ad = Ab + (size_t)buf * ASUBH;
        #pragma unroll
        for (int i = 0; i < AIPW; ++i) {
            int t  = (wave*AIPW + i)*64 + lane;
            int r  = t >> CPRS;
            int q  = t & (CPR - 1);
            int qq = q ^ SWZ(r);
            int gr = gidx[r*12 + sv];
            gload_lds16(xb + (size_t)gr*C_IN + c0 + qq*8,
                        Ad + (size_t)(wave*AIPW + i)*512);
        }
        _Float16* Bd = Bb + (size_t)buf * BSUBH;
        const _Float16* bs = Wp + ((size_t)(blockIdx.y*NST + g*GS)*4)*BN*8;
        #pragma unroll
        for (int i = 0; i < BIPW; ++i) {
            int t = (wave*BIPW + i)*64 + lane;
            gload_lds16(bs + (size_t)t*8,
                        Bd + (size_t)(wave*BIPW + i)*512);
        }
    };

    stage(0, 0);
    stage(1, 1);
    int cur = 0;

    for (int g = 0; g < NG; ++g) {
        // stage g (issued 2 groups ago) must have landed; g+1/g+2 stay in flight
        if (g + 1 < NG) vm_wait<LPW>(); else vm_wait<0>();
        __builtin_amdgcn_s_barrier();
        __builtin_amdgcn_sched_barrier(0);

        // buf[(cur+2)%3]'s readers finished at group g-1's bottom barrier
        int nx2 = cur + 2; if (nx2 >= NBUF) nx2 -= NBUF;
        if (g + 2 < NG) stage(g + 2, nx2);

        const _Float16* Ar = Ab + (size_t)cur * ASUBH;
        const _Float16* Br = Bb + (size_t)cur * BSUBH;
        #pragma unroll
        for (int sl = 0; sl < GS; ++sl) {
            f16x8 af[NMT], bf[NNT];
            #pragma unroll
            for (int i = 0; i < NMT; ++i) {
                int m = wm*WTM + i*16 + l16;
                af[i] = *(const f16x8*)&Ar[(size_t)(m*CPR + ((sl*4 + quad) ^ SWZ(m)))*8];
            }
            #pragma unroll
            for (int j = 0; j < NNT; ++j) {
                int n = wn*WTN + j*16 + l16;
                bf[j] = *(const f16x8*)&Br[(size_t)((sl*4 + quad)*BN + n)*8];
            }
            #pragma unroll
            for (int i = 0; i < NMT; ++i)
                #pragma unroll
                for (int j = 0; j < NNT; ++j)
                    acc[i][j] = __builtin_amdgcn_mfma_f32_16x16x32_f16(
                        af[i], bf[j], acc[i][j], 0, 0, 0);
        }

        // all waves done reading buf[cur] -> group g+1 may overwrite it
        asm volatile("s_waitcnt lgkmcnt(0)" ::: "memory");
        __builtin_amdgcn_sched_barrier(0);
        __builtin_amdgcn_s_barrier();
        __builtin_amdgcn_sched_barrier(0);
        cur = (cur + 1 == NBUF) ? 0 : cur + 1;
    }

    float bv[NNT];
    #pragma unroll
    for (int j = 0; j < NNT; ++j)
        bv[j] = bias[n0 + wn*WTN + j*16 + l16];

    #pragma unroll
    for (int i = 0; i < NMT; ++i) {
        int row_base = wm*WTM + i*16 + quad*4;
        #pragma unroll
        for (int j = 0; j < NNT; ++j) {
            int col = wn*WTN + j*16 + l16;
            #pragma unroll
            for (int r = 0; r < 4; ++r)
                E[(size_t)(row_base + r)*(BN+4) + col] =
                    (_Float16)elu_f(acc[i][j][r] + bv[j]);
        }
    }
    __syncthreads();

    #pragma unroll
    for (int e = tid; e < P*C4; e += 256) {
        int ul = e / C4;
        int c4 = e - ul*C4;
        int pu = pu0 + ul;
        int u  = pu & vmask_out;
        const float* w = dwt + u*3;
        f16x4 a0 = *(const f16x4*)&E[(size_t)(ul*3 + 0)*(BN+4) + c4*4];
        f16x4 a1 = *(const f16x4*)&E[(size_t)(ul*3 + 1)*(BN+4) + c4*4];
        f16x4 a2 = *(const f16x4*)&E[(size_t)(ul*3 + 2)*(BN+4) + c4*4];
        float ox = w[0]*(float)a0[0] + w[1]*(float)a1[0] + w[2]*(float)a2[0];
        float oy = w[0]*(float)a0[1] + w[1]*(float)a1[1] + w[2]*(float)a2[1];
        float oz = w[0]*(float)a0[2] + w[1]*(float)a1[2] + w[2]*(float)a2[2];
        float ow = w[0]*(float)a0[3] + w[1]*(float)a1[3] + w[2]*(float)a2[3];
        if (OUT_HALF) {
            f16x4 h; h[0]=(_Float16)ox; h[1]=(_Float16)oy; h[2]=(_Float16)oz; h[3]=(_Float16)ow;
            *(f16x4*)&((_Float16*)outv)[(size_t)pu*C_OUT + n0 + c4*4] = h;
        } else {
            float4 o; o.x=ox; o.y=oy; o.z=oz; o.w=ow;
            *(float4*)&((float*)outv)[(size_t)pu*C_OUT + n0 + c4*4] = o;
        }
    }
}

// ---------------- FC1: atomic-free split-K (ks=256, k-chunk 128) ----------------
__global__ __launch_bounds__(256)
void fc1_partial(const float* __restrict__ xflat, const float* __restrict__ Wl1,
                 float* __restrict__ partial)
{
    __shared__ float sb[8704];
    const int tid = threadIdx.x;
    const int n4 = tid & 31;
    const int kq = (tid >> 5) & 3;
    const int mh = tid >> 7;
    const int nt = blockIdx.x;
    const int ks = blockIdx.y;
    const int kbase = ks * 128;

    for (int e = tid; e < 1024; e += 256) {
        int m = e >> 5, k4 = e & 31;
        *(float4*)&sb[m*128 + k4*4] = *(const float4*)&xflat[(size_t)m*32768 + kbase + k4*4];
    }
    __syncthreads();

    float acc[16][4];
    #pragma unroll
    for (int m = 0; m < 16; ++m)
        #pragma unroll
        for (int c = 0; c < 4; ++c) acc[m][c] = 0.0f;

    const float* Wb = Wl1 + (size_t)(kbase + kq*32)*512 + nt*128 + n4*4;
    #pragma unroll 2
    for (int i = 0; i < 32; i += 4) {
        float4 w0 = *(const float4*)(Wb + (size_t)(i+0)*512);
        float4 w1 = *(const float4*)(Wb + (size_t)(i+1)*512);
        float4 w2 = *(const float4*)(Wb + (size_t)(i+2)*512);
        float4 w3 = *(const float4*)(Wb + (size_t)(i+3)*512);
        #pragma unroll
        for (int m = 0; m < 16; ++m) {
            float4 xv = *(const float4*)&sb[(mh*16 + m)*128 + kq*32 + i];
            acc[m][0] += xv.x*w0.x + xv.y*w1.x + xv.z*w2.x + xv.w*w3.x;
            acc[m][1] += xv.x*w0.y + xv.y*w1.y + xv.z*w2.y + xv.w*w3.y;
            acc[m][2] += xv.x*w0.z + xv.y*w1.z + xv.z*w2.z + xv.w*w3.z;
            acc[m][3] += xv.x*w0.w + xv.y*w1.w + xv.z*w2.w + xv.w*w3.w;
        }
    }
    __syncthreads();

    int slot = (mh*2 + (kq >> 1))*32 + n4;
    if (kq & 1) {
        #pragma unroll
        for (int m = 0; m < 16; ++m)
            *(float4*)&sb[slot*68 + m*4] = *(float4*)&acc[m][0];
    }
    __syncthreads();
    if (!(kq & 1)) {
        #pragma unroll
        for (int m = 0; m < 16; ++m) {
            float4 v = *(const float4*)&sb[slot*68 + m*4];
            acc[m][0] += v.x; acc[m][1] += v.y; acc[m][2] += v.z; acc[m][3] += v.w;
        }
    }
    __syncthreads();
    int slot2 = mh*32 + n4;
    if (kq == 2) {
        #pragma unroll
        for (int m = 0; m < 16; ++m)
            *(float4*)&sb[slot2*68 + m*4] = *(float4*)&acc[m][0];
    }
    __syncthreads();
    if (kq == 0) {
        float* pb = partial + ((size_t)(ks*4 + nt)*32 + mh*16)*128 + n4*4;
        #pragma unroll
        for (int m = 0; m < 16; ++m) {
            float4 v = *(const float4*)&sb[slot2*68 + m*4];
            float4 o;
            o.x = acc[m][0] + v.x; o.y = acc[m][1] + v.y;
            o.z = acc[m][2] + v.z; o.w = acc[m][3] + v.w;
            *(float4*)(pb + (size_t)m*128) = o;
        }
    }
}

__global__ __launch_bounds__(256)
void fc1_reduce(const float* __restrict__ partial, const float* __restrict__ bl1,
                float* __restrict__ hout)
{
    int i = blockIdx.x * 256 + threadIdx.x;
    int m = i >> 9, n = i & 511;
    int nt = n >> 7, nl = n & 127;
    const float* p = partial + ((size_t)nt*32 + m)*128 + nl;
    float s = 0.0f;
    #pragma unroll 8
    for (int ks = 0; ks < 256; ++ks)
        s += p[(size_t)ks*4*4096];
    hout[i] = elu_f(s + bl1[n]);
}

__global__ __launch_bounds__(64)
void fc2_kernel(const float* __restrict__ h, const float* __restrict__ Wl2,
                const float* __restrict__ bl2, float* __restrict__ y)
{
    int m = blockIdx.x;
    int n = threadIdx.x;
    float s = bl2[n];
    for (int k = 0; k < 512; ++k)
        s += h[(size_t)m*512 + k] * Wl2[(size_t)k*64 + n];
    y[(size_t)m*64 + n] = s;
}

extern "C" void kernel_launch(void* const* d_in, const int* in_sizes, int n_in,
                              void* d_out, int out_size, void* d_ws, size_t ws_size,
                              hipStream_t stream)
{
    (void)in_sizes; (void)n_in; (void)out_size; (void)ws_size;

    const float* x0 = (const float*)d_in[0];
    const int*   sp[4]; const int* didx[4]; const float* dwp[4];
    const float* Wp[4]; const float* bp[4];
    for (int i = 0; i < 4; ++i) {
        sp[i]   = (const int*)  d_in[1 + i*5 + 0];
        didx[i] = (const int*)  d_in[1 + i*5 + 1];
        dwp[i]  = (const float*)d_in[1 + i*5 + 2];
        Wp[i]   = (const float*)d_in[1 + i*5 + 3];
        bp[i]   = (const float*)d_in[1 + i*5 + 4];
    }
    const float* Wl1 = (const float*)d_in[21];
    const float* bl1 = (const float*)d_in[22];
    const float* Wl2 = (const float*)d_in[23];
    const float* bl2 = (const float*)d_in[24];
    float* out = (float*)d_out;

    char* wsb = (char*)d_ws;
    float* persist      = (float*)wsb;                    // 4 MB   (32,128,256) fp32
    float* partial      = (float*)(wsb + (4<<20));        // 16.8 MB (1024 x 4096 f32)
    _Float16* xT        = (_Float16*)(wsb + (24<<20));    // 8 MB   (2 halves x 4 MB)
    _Float16* pooled0   = (_Float16*)(wsb + (32<<20));    // 16 MB  (32,8192,32) fp16
    _Float16* pooled1   = (_Float16*)(wsb + (48<<20));    // 8 MB   (32,2048,64) fp16
    _Float16* pooled2   = (_Float16*)(wsb + (56<<20));    // 4 MB   (32,512,128) fp16
    unsigned int* gidx0 = (unsigned int*)(wsb + (60<<20));// 0.75 MB
    _Float16* w0h       = (_Float16*)(wsb + (61<<20));
    _Float16* w1h       = w0h + 2048;
    _Float16* w2h       = w1h + 24576;
    _Float16* w3h       = w2h + 98304;

    prep_w0<<<8, 256, 0, stream>>>(Wp[0], w0h);
    prep_w< 384,  64,  64><<<( 24576 + 255)/256, 256, 0, stream>>>(Wp[1], w1h);
    prep_w< 768, 128,  64><<<( 98304 + 255)/256, 256, 0, stream>>>(Wp[2], w2h);
    prep_w<1536, 256,  64><<<(393216 + 255)/256, 256, 0, stream>>>(Wp[3], w3h);
    prep_gidx<<<768, 256, 0, stream>>>(didx[0], sp[0], gidx0);

    // L0: x transpose + batched-M conv0 (2 dispatches of 16 batches each)
    for (int h = 0; h < 2; ++h) {
        _Float16* xTh = xT + (size_t)h*2097152;
        prep_xT<<<512, 256, 0, stream>>>(x0 + (size_t)h*16*98304, xTh);
        conv0T<<<1024, 256, 0, stream>>>(xTh, gidx0, w0h, bp[0], dwp[0],
                                         pooled0 + (size_t)h*16*262144);
    }

    // L1: conv(32->64, K=384) + pool -> fp16 (32, 2048, 64)   [3-buf counted-vmcnt]
    conv_pool_mfma<32,64,64,64,4,1,true><<<1024, 256, 0, stream>>>(
        pooled0, sp[1], w1h, bp[1], didx[1], dwp[1], pooled1, 13, 11, 2);

    // L2: conv(64->128, K=768) + pool -> fp16 (32, 512, 128)  [BN=64 so 3 bufs fit]
    conv_pool_mfma<64,128,32,64,2,2,true><<<dim3(512, 2), 256, 0, stream>>>(
        pooled1, sp[2], w2h, bp[2], didx[2], dwp[2], pooled2, 11, 9, 2);

    // L3: conv(128->256, K=1536) + pool -> fp32 persist (32, 128, 256)
    conv_pool_mfma<128,256,32,64,2,2,false><<<dim3(128, 4), 256, 0, stream>>>(
        pooled2, sp[3], w3h, bp[3], didx[3], dwp[3], persist, 9, 7, 2);

    // FC1: (32,32768)@(32768,512), split-K partials then reduce+bias+ELU
    fc1_partial<<<dim3(4, 256), 256, 0, stream>>>(persist, Wl1, partial);
    fc1_reduce<<<64, 256, 0, stream>>>(partial, bl1, out);

    // FC2: (32,512)@(512,64) + bias -> d_out[16384:18432]
    fc2_kernel<<<32, 64, 0, stream>>>(out, Wl2, bl2, out + 16384);
}

// Round 7
// 283.806 us; speedup vs baseline: 1.0642x; 1.0642x over previous
//
#include <hip/hip_runtime.h>
#include <cstdint>
#include <cstddef>

typedef _Float16 f16x8 __attribute__((ext_vector_type(8)));
typedef _Float16 f16x4 __attribute__((ext_vector_type(4)));
typedef float f32x4 __attribute__((ext_vector_type(4)));

static __device__ __forceinline__ float elu_f(float t) {
    return t > 0.0f ? t : expm1f(t);
}

// async global->LDS 16B copy: per-lane GLOBAL source, linear LDS dest
// (wave-uniform base + lane*16).
typedef __attribute__((address_space(1))) const unsigned int guint;
typedef __attribute__((address_space(3))) unsigned int       luint;
static __device__ __forceinline__ void gload_lds16(const void* g, void* l)
{
    __builtin_amdgcn_global_load_lds((guint*)g, (luint*)l, 16, 0, 0);
}

// counted vmcnt wait (T4): literal immediates only, fenced per rule #18.
template<int N>
static __device__ __forceinline__ void vm_wait()
{
    static_assert(N == 0 || N == 4 || N == 5, "vmcnt literal");
    if constexpr (N == 0)      asm volatile("s_waitcnt vmcnt(0)" ::: "memory");
    else if constexpr (N == 4) asm volatile("s_waitcnt vmcnt(4)" ::: "memory");
    else                       asm volatile("s_waitcnt vmcnt(5)" ::: "memory");
    __builtin_amdgcn_sched_barrier(0);
}

// XCD-aware block -> pooled-vertex-tile remap (XCD = bid & 7 round-robin).
static __device__ __forceinline__ int block_pu0(int bid, int P, int vshift_out, int nbl)
{
    if (nbl < 0) return bid * P;
    int xcd  = bid & 7;
    int slot = bid >> 3;
    int nb   = slot & ((1 << nbl) - 1);
    int tile = slot >> nbl;
    return ((xcd + (nb << 3)) << vshift_out) + tile * P;
}

// ---------------- fused weight/index prep (was 5 dispatches, now 1) ----------------
template<int KTOT, int C_OUT, int BN>
static __device__ __forceinline__ void prep_w_body(const float* __restrict__ W,
                                                   _Float16* __restrict__ o, int i)
{
    constexpr int KT = KTOT/64;
    int j = i & 7;
    int rest = i >> 3;
    int n = rest % BN;
    int kc = (rest / BN) & 7;
    int t = (rest / (BN*8)) % KT;
    int y = rest / (BN*8*KT);
    int k = t*64 + kc*8 + j;
    o[i] = (_Float16)W[(size_t)k*C_OUT + y*BN + n];
}

__global__ __launch_bounds__(256)
void prep_all(const float* __restrict__ W0, const float* __restrict__ W1,
              const float* __restrict__ W2, const float* __restrict__ W3,
              const int* __restrict__ didx0, const int* __restrict__ spiral0,
              _Float16* __restrict__ w0h, _Float16* __restrict__ w1h,
              _Float16* __restrict__ w2h, _Float16* __restrict__ w3h,
              unsigned int* __restrict__ g)
{
    const int bid = blockIdx.x;
    const int tid = threadIdx.x;
    if (bid < 8) {
        // level-0 weights: (36,32) -> padded K=64, k = s*4+c, tile [kc][n][8]
        int i = bid*256 + tid;                 // 2048
        int j = i & 7;
        int n = (i >> 3) & 31;
        int kc = i >> 8;
        int k = kc*8 + j;
        int s = k >> 2, c = k & 3;
        float v = (s < 12 && c < 3) ? W0[(size_t)(s*3 + c)*32 + n] : 0.0f;
        w0h[i] = (_Float16)v;
    } else if (bid < 104) {
        prep_w_body< 384,  64, 64>(W1, w1h, (bid - 8)*256 + tid);     // 24576
    } else if (bid < 488) {
        prep_w_body< 768, 128, 64>(W2, w2h, (bid - 104)*256 + tid);   // 98304
    } else if (bid < 2024) {
        prep_w_body<1536, 256, 64>(W3, w3h, (bid - 488)*256 + tid);   // 393216
    } else {
        // didx0 o spiral0 -> u16-pair table (24576 rows x 8)
        int i = (bid - 2024)*256 + tid;        // 196608
        int q = i & 7;
        int row = i >> 3;
        unsigned int val = 0;
        if (q < 6) {
            int v = didx0[row];
            unsigned int s0 = (unsigned int)spiral0[v*12 + q*2];
            unsigned int s1 = (unsigned int)spiral0[v*12 + q*2 + 1];
            val = s0 | (s1 << 16);
        }
        g[i] = val;
    }
}

// ---------------- x transpose, both halves: (32,32768,3) fp32 -> 2x(32768,16,4) fp16 ----------------
__global__ __launch_bounds__(256)
void prep_xT(const float* __restrict__ x0, _Float16* __restrict__ xT)
{
    __shared__ _Float16 t[16][64*4 + 8];
    const int h  = blockIdx.x >> 9;
    const float* x = x0 + (size_t)h*16*98304;
    _Float16* xTh  = xT + (size_t)h*2097152;
    const int v0 = (blockIdx.x & 511) * 64;
    const int tid = threadIdx.x;
    #pragma unroll
    for (int it = 0; it < 4; ++it) {
        int e = it*256 + tid;          // 16 b x 64 v
        int b = e >> 6, v = e & 63;
        const float* p = x + ((size_t)b*32768 + v0 + v)*3;
        f16x4 hh;
        hh[0] = (_Float16)p[0]; hh[1] = (_Float16)p[1];
        hh[2] = (_Float16)p[2]; hh[3] = (_Float16)0.f;
        *(f16x4*)&t[b][v*4] = hh;
    }
    __syncthreads();
    #pragma unroll
    for (int it = 0; it < 2; ++it) {
        int e = it*256 + tid;          // 64 v x 8 s
        int vl = e >> 3, s = e & 7;
        f16x4 a = *(const f16x4*)&t[2*s][vl*4];
        f16x4 b = *(const f16x4*)&t[2*s+1][vl*4];
        f16x8 hh;
        hh[0]=a[0]; hh[1]=a[1]; hh[2]=a[2]; hh[3]=a[3];
        hh[4]=b[0]; hh[5]=b[1]; hh[6]=b[2]; hh[7]=b[3];
        *(f16x8*)&xTh[((size_t)(v0+vl)*16 + s*2)*4] = hh;
    }
}

// ---------------- conv0+pool0, both halves, batched-M over 16 batches ----------------
__global__ __launch_bounds__(256)
void conv0T(const _Float16* __restrict__ xT0, const unsigned int* __restrict__ gidx,
            const _Float16* __restrict__ Wp, const float* __restrict__ bias,
            const float* __restrict__ dwt, _Float16* __restrict__ out0)
{
    __shared__ _Float16 Ep[4][512];        // per-wave 1 KB transpose buffer
    const int h = blockIdx.x >> 10;
    const _Float16* xT = xT0 + (size_t)h*2097152;
    _Float16* out = out0 + (size_t)h*16*262144;
    const int tid  = threadIdx.x;
    const int wave = tid >> 6;
    const int lane = tid & 63;
    const int quad = lane >> 4;
    const int l16  = lane & 15;
    const int u0   = (blockIdx.x & 1023) * 8 + wave * 2;   // 2 u per wave

    f16x8 bf[2][2];
    #pragma unroll
    for (int kt = 0; kt < 2; ++kt)
        #pragma unroll
        for (int nt = 0; nt < 2; ++nt)
            bf[kt][nt] = *(const f16x8*)&Wp[(((kt*4+quad)*32) + nt*16 + l16)*8];
    float bv[2] = { bias[l16], bias[16 + l16] };

    #pragma unroll
    for (int ui = 0; ui < 2; ++ui) {
        int u = u0 + ui;
        f32x4 pacc[2] = {{0.f,0.f,0.f,0.f},{0.f,0.f,0.f,0.f}};
        #pragma unroll
        for (int kp = 0; kp < 3; ++kp) {
            int r = u*3 + kp;
            unsigned int gp0 = gidx[r*8 + quad];
            unsigned int gp1 = gidx[r*8 + 4 + quad];
            f16x4 a0 = *(const f16x4*)&xT[(size_t)(gp0 & 0xffffu)*64 + l16*4];
            f16x4 a1 = *(const f16x4*)&xT[(size_t)(gp0 >> 16)*64 + l16*4];
            f16x4 a2 = *(const f16x4*)&xT[(size_t)(gp1 & 0xffffu)*64 + l16*4];
            f16x4 a3 = *(const f16x4*)&xT[(size_t)(gp1 >> 16)*64 + l16*4];
            f16x8 af0, af1;
            af0[0]=a0[0]; af0[1]=a0[1]; af0[2]=a0[2]; af0[3]=a0[3];
            af0[4]=a1[0]; af0[5]=a1[1]; af0[6]=a1[2]; af0[7]=a1[3];
            af1[0]=a2[0]; af1[1]=a2[1]; af1[2]=a2[2]; af1[3]=a2[3];
            af1[4]=a3[0]; af1[5]=a3[1]; af1[6]=a3[2]; af1[7]=a3[3];
            float dw = dwt[r];
            #pragma unroll
            for (int nt = 0; nt < 2; ++nt) {
                f32x4 m = {0.f,0.f,0.f,0.f};
                m = __builtin_amdgcn_mfma_f32_16x16x32_f16(af0, bf[0][nt], m, 0,0,0);
                m = __builtin_amdgcn_mfma_f32_16x16x32_f16(af1, bf[1][nt], m, 0,0,0);
                #pragma unroll
                for (int rr = 0; rr < 4; ++rr)
                    pacc[nt][rr] += dw * elu_f(m[rr] + bv[nt]);
            }
        }
        #pragma unroll
        for (int nt = 0; nt < 2; ++nt)
            #pragma unroll
            for (int rr = 0; rr < 4; ++rr)
                Ep[wave][(quad*4+rr)*32 + nt*16 + l16] = (_Float16)pacc[nt][rr];
        int b  = lane >> 2;
        int c8 = lane & 3;
        f16x8 rowv = *(const f16x8*)&Ep[wave][b*32 + c8*8];
        *(f16x8*)&out[(size_t)b*262144 + (size_t)u*32 + c8*8] = rowv;
    }
}

// ---------------- fused conv+pool: multi-buffer LDS staging, COUNTED vmcnt ----------------
// Round-5 post-mortem: counted-vmcnt pipeline works (L2 43.8 -> <40us) but L1's
// NBUF=3 grew LDS 37.4->53.8KB, halving occupancy 4->2 blocks/CU -> net loss.
// Per-level NBUF: L1 uses NBUF=2 (depth-1 counted wait, 37.4KB, 4 blocks/CU);
// L2/L3 keep NBUF=3 (depth-2, 2 blocks/CU, measured better than drain-0).
// Ledger: the K-loop's only VMEM ops are the stage's own LPW loads; pre-loop
// gather loads are drained by the __syncthreads after gidx staging.
// MFMA order per K-step unchanged -> identical numerics.
template<int C_IN, int C_OUT, int P, int BN, int WGM, int WGN, bool OUT_HALF, int NBUF>
__global__ __launch_bounds__(256)
void conv_pool_mfma(const _Float16* __restrict__ x, const int* __restrict__ spiral,
                    const _Float16* __restrict__ Wp, const float* __restrict__ bias,
                    const int* __restrict__ didx, const float* __restrict__ dwt,
                    void* __restrict__ outv, int vshift_in, int vshift_out, int nbl)
{
    constexpr int R    = 3*P;
    constexpr int KTOT = 12*C_IN;
    constexpr int KT   = KTOT/64;
    constexpr int NST  = KT*2;           // number of K=32 steps
    constexpr int WTM  = R/WGM;
    constexpr int WTN  = BN/WGN;
    constexpr int NMT  = WTM/16;
    constexpr int NNT  = WTN/16;
    constexpr int C4   = BN/4;
    constexpr int GS   = (C_IN == 32) ? 1 : 2;   // K-steps per staging group
    constexpr int NG   = NST / GS;
    constexpr int CPR  = GS * 4;         // 16B chunks per staged row-part (4 or 8)
    constexpr int CPRS = (CPR == 4) ? 2 : 3;
    constexpr int ACH  = R * CPR;        // A chunks per group
    constexpr int BCH  = GS * BN * 4;    // B chunks per group
    constexpr int AIPW = ACH / 256;      // global_load_lds instrs per wave
    constexpr int BIPW = BCH / 256;
    constexpr int LPW  = AIPW + BIPW;    // own loads per stage (vmcnt unit)
    constexpr int ASUBH = R * GS * 32;   // halfs per A sub-buffer
    constexpr int BSUBH = GS * 32 * BN;  // halfs per B sub-buffer
    static_assert(WTM % 16 == 0 && WTN % 16 == 0, "tile");
    static_assert(R <= 256 && (P*C4) % 256 == 0, "loops");
    static_assert(ACH % 256 == 0 && BCH % 256 == 0, "stage");
    static_assert(NST % GS == 0 && GS*32 <= C_IN, "group");
    static_assert(NBUF == 2 || NBUF == 3, "nbuf");
    static_assert(NBUF == 2 ? NG >= 2 : NG >= 3, "pipeline depth");

    constexpr size_t BUFB = (size_t)(NBUF*(ASUBH + BSUBH)) * 2;
    constexpr size_t EB   = (size_t)R * (BN + 4) * 2;
    constexpr size_t GOFF = (BUFB > EB ? BUFB : EB);
    static_assert(GOFF + (size_t)R*12*2 <= 65536, "LDS budget");
    __shared__ __align__(16) char smem[GOFF + (size_t)R*12*2];
    _Float16* Ab = (_Float16*)smem;
    _Float16* Bb = (_Float16*)(smem + (size_t)NBUF*ASUBH*2);
    unsigned short* gidx = (unsigned short*)(smem + GOFF);
    _Float16* E = (_Float16*)smem;       // overlays staging bufs (dead after K-loop)

    const int tid  = threadIdx.x;
    const int wave = tid >> 6;
    const int lane = tid & 63;
    const int quad = lane >> 4;
    const int l16  = lane & 15;
    const int wm   = wave / WGN;
    const int wn   = wave % WGN;
    const int pu0  = block_pu0(blockIdx.x, P, vshift_out, nbl);
    const int n0   = blockIdx.y * BN;
    const int vmask_out = (1 << vshift_out) - 1;
    const int base_in = (pu0 >> vshift_out) << vshift_in;

    if (tid < R) {
        int ul = tid / 3;
        int kp = tid - ul*3;
        int u  = (pu0 + ul) & vmask_out;
        int v  = didx[u*3 + kp];
        const int* svp = spiral + v*12;
        #pragma unroll
        for (int j = 0; j < 12; ++j) gidx[tid*12 + j] = (unsigned short)svp[j];
    }
    __syncthreads();   // also drains the gather loads above (vmcnt ledger reset)

    f32x4 acc[NMT][NNT];
    #pragma unroll
    for (int i = 0; i < NMT; ++i)
        #pragma unroll
        for (int j = 0; j < NNT; ++j) acc[i][j] = (f32x4){0.f, 0.f, 0.f, 0.f};

    const _Float16* xb = x + (size_t)base_in * C_IN;

    // chunk swizzle: slot q of row r holds global chunk q ^ SWZ(r)
    auto SWZ = [](int r) -> int {
        return (CPR == 4) ? ((r & 3) ^ ((r >> 2) & 3)) : (r & 7);
    };

    auto stage = [&](int g, int buf) {
        const int k0g = g * GS * 32;
        const int sv  = k0g / C_IN;
        const int c0  = k0g % C_IN;                  // halfs
        _Float16* Ad = Ab + (size_t)buf * ASUBH;
        #pragma unroll
        for (int i = 0; i < AIPW; ++i) {
            int t  = (wave*AIPW + i)*64 + lane;
            int r  = t >> CPRS;
            int q  = t & (CPR - 1);
            int qq = q ^ SWZ(r);
            int gr = gidx[r*12 + sv];
            gload_lds16(xb + (size_t)gr*C_IN + c0 + qq*8,
                        Ad + (size_t)(wave*AIPW + i)*512);
        }
        _Float16* Bd = Bb + (size_t)buf * BSUBH;
        const _Float16* bs = Wp + ((size_t)(blockIdx.y*NST + g*GS)*4)*BN*8;
        #pragma unroll
        for (int i = 0; i < BIPW; ++i) {
            int t = (wave*BIPW + i)*64 + lane;
            gload_lds16(bs + (size_t)t*8,
                        Bd + (size_t)(wave*BIPW + i)*512);
        }
    };

    auto compute = [&](int cb) {
        const _Float16* Ar = Ab + (size_t)cb * ASUBH;
        const _Float16* Br = Bb + (size_t)cb * BSUBH;
        #pragma unroll
        for (int sl = 0; sl < GS; ++sl) {
            f16x8 af[NMT], bf[NNT];
            #pragma unroll
            for (int i = 0; i < NMT; ++i) {
                int m = wm*WTM + i*16 + l16;
                af[i] = *(const f16x8*)&Ar[(size_t)(m*CPR + ((sl*4 + quad) ^ SWZ(m)))*8];
            }
            #pragma unroll
            for (int j = 0; j < NNT; ++j) {
                int n = wn*WTN + j*16 + l16;
                bf[j] = *(const f16x8*)&Br[(size_t)((sl*4 + quad)*BN + n)*8];
            }
            #pragma unroll
            for (int i = 0; i < NMT; ++i)
                #pragma unroll
                for (int j = 0; j < NNT; ++j)
                    acc[i][j] = __builtin_amdgcn_mfma_f32_16x16x32_f16(
                        af[i], bf[j], acc[i][j], 0, 0, 0);
        }
    };

    if constexpr (NBUF == 3) {
        stage(0, 0);
        stage(1, 1);
        int cur = 0;
        for (int g = 0; g < NG; ++g) {
            if (g + 1 < NG) vm_wait<LPW>(); else vm_wait<0>();
            __builtin_amdgcn_s_barrier();
            __builtin_amdgcn_sched_barrier(0);
            int nx2 = cur + 2; if (nx2 >= 3) nx2 -= 3;
            if (g + 2 < NG) stage(g + 2, nx2);
            compute(cur);
            asm volatile("s_waitcnt lgkmcnt(0)" ::: "memory");
            __builtin_amdgcn_sched_barrier(0);
            __builtin_amdgcn_s_barrier();
            __builtin_amdgcn_sched_barrier(0);
            cur = (cur + 1 == 3) ? 0 : cur + 1;
        }
    } else {
        stage(0, 0);
        int cur = 0;
        for (int g = 0; g < NG; ++g) {
            if (g + 1 < NG) {
                stage(g + 1, cur ^ 1);   // buf cur^1's readers done at g-1 bottom
                vm_wait<LPW>();          // stage g landed, g+1 stays in flight
            } else {
                vm_wait<0>();
            }
            __builtin_amdgcn_s_barrier();
            __builtin_amdgcn_sched_barrier(0);
            compute(cur);
            asm volatile("s_waitcnt lgkmcnt(0)" ::: "memory");
            __builtin_amdgcn_sched_barrier(0);
            __builtin_amdgcn_s_barrier();
            __builtin_amdgcn_sched_barrier(0);
            cur ^= 1;
        }
    }

    float bv[NNT];
    #pragma unroll
    for (int j = 0; j < NNT; ++j)
        bv[j] = bias[n0 + wn*WTN + j*16 + l16];

    #pragma unroll
    for (int i = 0; i < NMT; ++i) {
        int row_base = wm*WTM + i*16 + quad*4;
        #pragma unroll
        for (int j = 0; j < NNT; ++j) {
            int col = wn*WTN + j*16 + l16;
            #pragma unroll
            for (int r = 0; r < 4; ++r)
                E[(size_t)(row_base + r)*(BN+4) + col] =
                    (_Float16)elu_f(acc[i][j][r] + bv[j]);
        }
    }
    __syncthreads();

    #pragma unroll
    for (int e = tid; e < P*C4; e += 256) {
        int ul = e / C4;
        int c4 = e - ul*C4;
        int pu = pu0 + ul;
        int u  = pu & vmask_out;
        const float* w = dwt + u*3;
        f16x4 a0 = *(const f16x4*)&E[(size_t)(ul*3 + 0)*(BN+4) + c4*4];
        f16x4 a1 = *(const f16x4*)&E[(size_t)(ul*3 + 1)*(BN+4) + c4*4];
        f16x4 a2 = *(const f16x4*)&E[(size_t)(ul*3 + 2)*(BN+4) + c4*4];
        float ox = w[0]*(float)a0[0] + w[1]*(float)a1[0] + w[2]*(float)a2[0];
        float oy = w[0]*(float)a0[1] + w[1]*(float)a1[1] + w[2]*(float)a2[1];
        float oz = w[0]*(float)a0[2] + w[1]*(float)a1[2] + w[2]*(float)a2[2];
        float ow = w[0]*(float)a0[3] + w[1]*(float)a1[3] + w[2]*(float)a2[3];
        if (OUT_HALF) {
            f16x4 h; h[0]=(_Float16)ox; h[1]=(_Float16)oy; h[2]=(_Float16)oz; h[3]=(_Float16)ow;
            *(f16x4*)&((_Float16*)outv)[(size_t)pu*C_OUT + n0 + c4*4] = h;
        } else {
            float4 o; o.x=ox; o.y=oy; o.z=oz; o.w=ow;
            *(float4*)&((float*)outv)[(size_t)pu*C_OUT + n0 + c4*4] = o;
        }
    }
}

// ---------------- FC1: atomic-free split-K (ks=256, k-chunk 128) ----------------
__global__ __launch_bounds__(256)
void fc1_partial(const float* __restrict__ xflat, const float* __restrict__ Wl1,
                 float* __restrict__ partial)
{
    __shared__ float sb[8704];
    const int tid = threadIdx.x;
    const int n4 = tid & 31;
    const int kq = (tid >> 5) & 3;
    const int mh = tid >> 7;
    const int nt = blockIdx.x;
    const int ks = blockIdx.y;
    const int kbase = ks * 128;

    for (int e = tid; e < 1024; e += 256) {
        int m = e >> 5, k4 = e & 31;
        *(float4*)&sb[m*128 + k4*4] = *(const float4*)&xflat[(size_t)m*32768 + kbase + k4*4];
    }
    __syncthreads();

    float acc[16][4];
    #pragma unroll
    for (int m = 0; m < 16; ++m)
        #pragma unroll
        for (int c = 0; c < 4; ++c) acc[m][c] = 0.0f;

    const float* Wb = Wl1 + (size_t)(kbase + kq*32)*512 + nt*128 + n4*4;
    #pragma unroll 2
    for (int i = 0; i < 32; i += 4) {
        float4 w0 = *(const float4*)(Wb + (size_t)(i+0)*512);
        float4 w1 = *(const float4*)(Wb + (size_t)(i+1)*512);
        float4 w2 = *(const float4*)(Wb + (size_t)(i+2)*512);
        float4 w3 = *(const float4*)(Wb + (size_t)(i+3)*512);
        #pragma unroll
        for (int m = 0; m < 16; ++m) {
            float4 xv = *(const float4*)&sb[(mh*16 + m)*128 + kq*32 + i];
            acc[m][0] += xv.x*w0.x + xv.y*w1.x + xv.z*w2.x + xv.w*w3.x;
            acc[m][1] += xv.x*w0.y + xv.y*w1.y + xv.z*w2.y + xv.w*w3.y;
            acc[m][2] += xv.x*w0.z + xv.y*w1.z + xv.z*w2.z + xv.w*w3.z;
            acc[m][3] += xv.x*w0.w + xv.y*w1.w + xv.z*w2.w + xv.w*w3.w;
        }
    }
    __syncthreads();

    int slot = (mh*2 + (kq >> 1))*32 + n4;
    if (kq & 1) {
        #pragma unroll
        for (int m = 0; m < 16; ++m)
            *(float4*)&sb[slot*68 + m*4] = *(float4*)&acc[m][0];
    }
    __syncthreads();
    if (!(kq & 1)) {
        #pragma unroll
        for (int m = 0; m < 16; ++m) {
            float4 v = *(const float4*)&sb[slot*68 + m*4];
            acc[m][0] += v.x; acc[m][1] += v.y; acc[m][2] += v.z; acc[m][3] += v.w;
        }
    }
    __syncthreads();
    int slot2 = mh*32 + n4;
    if (kq == 2) {
        #pragma unroll
        for (int m = 0; m < 16; ++m)
            *(float4*)&sb[slot2*68 + m*4] = *(float4*)&acc[m][0];
    }
    __syncthreads();
    if (kq == 0) {
        float* pb = partial + ((size_t)(ks*4 + nt)*32 + mh*16)*128 + n4*4;
        #pragma unroll
        for (int m = 0; m < 16; ++m) {
            float4 v = *(const float4*)&sb[slot2*68 + m*4];
            float4 o;
            o.x = acc[m][0] + v.x; o.y = acc[m][1] + v.y;
            o.z = acc[m][2] + v.z; o.w = acc[m][3] + v.w;
            *(float4*)(pb + (size_t)m*128) = o;
        }
    }
}

__global__ __launch_bounds__(256)
void fc1_reduce(const float* __restrict__ partial, const float* __restrict__ bl1,
                float* __restrict__ hout)
{
    int i = blockIdx.x * 256 + threadIdx.x;
    int m = i >> 9, n = i & 511;
    int nt = n >> 7, nl = n & 127;
    const float* p = partial + ((size_t)nt*32 + m)*128 + nl;
    float s = 0.0f;
    #pragma unroll 8
    for (int ks = 0; ks < 256; ++ks)
        s += p[(size_t)ks*4*4096];
    hout[i] = elu_f(s + bl1[n]);
}

__global__ __launch_bounds__(64)
void fc2_kernel(const float* __restrict__ h, const float* __restrict__ Wl2,
                const float* __restrict__ bl2, float* __restrict__ y)
{
    int m = blockIdx.x;
    int n = threadIdx.x;
    float s = bl2[n];
    for (int k = 0; k < 512; ++k)
        s += h[(size_t)m*512 + k] * Wl2[(size_t)k*64 + n];
    y[(size_t)m*64 + n] = s;
}

extern "C" void kernel_launch(void* const* d_in, const int* in_sizes, int n_in,
                              void* d_out, int out_size, void* d_ws, size_t ws_size,
                              hipStream_t stream)
{
    (void)in_sizes; (void)n_in; (void)out_size; (void)ws_size;

    const float* x0 = (const float*)d_in[0];
    const int*   sp[4]; const int* didx[4]; const float* dwp[4];
    const float* Wp[4]; const float* bp[4];
    for (int i = 0; i < 4; ++i) {
        sp[i]   = (const int*)  d_in[1 + i*5 + 0];
        didx[i] = (const int*)  d_in[1 + i*5 + 1];
        dwp[i]  = (const float*)d_in[1 + i*5 + 2];
        Wp[i]   = (const float*)d_in[1 + i*5 + 3];
        bp[i]   = (const float*)d_in[1 + i*5 + 4];
    }
    const float* Wl1 = (const float*)d_in[21];
    const float* bl1 = (const float*)d_in[22];
    const float* Wl2 = (const float*)d_in[23];
    const float* bl2 = (const float*)d_in[24];
    float* out = (float*)d_out;

    char* wsb = (char*)d_ws;
    float* persist      = (float*)wsb;                    // 4 MB   (32,128,256) fp32
    float* partial      = (float*)(wsb + (4<<20));        // 16.8 MB (1024 x 4096 f32)
    _Float16* xT        = (_Float16*)(wsb + (24<<20));    // 8 MB   (2 halves x 4 MB)
    _Float16* pooled0   = (_Float16*)(wsb + (32<<20));    // 16 MB  (32,8192,32) fp16
    _Float16* pooled1   = (_Float16*)(wsb + (48<<20));    // 8 MB   (32,2048,64) fp16
    _Float16* pooled2   = (_Float16*)(wsb + (56<<20));    // 4 MB   (32,512,128) fp16
    unsigned int* gidx0 = (unsigned int*)(wsb + (60<<20));// 0.75 MB
    _Float16* w0h       = (_Float16*)(wsb + (61<<20));
    _Float16* w1h       = w0h + 2048;
    _Float16* w2h       = w1h + 24576;
    _Float16* w3h       = w2h + 98304;

    // all weight/index prep in ONE dispatch (was 5)
    prep_all<<<2792, 256, 0, stream>>>(Wp[0], Wp[1], Wp[2], Wp[3],
                                       didx[0], sp[0],
                                       w0h, w1h, w2h, w3h, gidx0);

    // L0: x transpose (both halves, 1 dispatch) + conv0 (both halves, 1 dispatch)
    prep_xT<<<1024, 256, 0, stream>>>(x0, xT);
    conv0T<<<2048, 256, 0, stream>>>(xT, gidx0, w0h, bp[0], dwp[0], pooled0);

    // L1: conv(32->64, K=384) + pool -> fp16 (32, 2048, 64)
    //     NBUF=2 counted (37.4KB LDS -> 4 blocks/CU)
    conv_pool_mfma<32,64,64,64,4,1,true,2><<<1024, 256, 0, stream>>>(
        pooled0, sp[1], w1h, bp[1], didx[1], dwp[1], pooled1, 13, 11, 2);

    // L2: conv(64->128, K=768) + pool -> fp16 (32, 512, 128)  [NBUF=3 depth-2]
    conv_pool_mfma<64,128,32,64,2,2,true,3><<<dim3(512, 2), 256, 0, stream>>>(
        pooled1, sp[2], w2h, bp[2], didx[2], dwp[2], pooled2, 11, 9, 2);

    // L3: conv(128->256, K=1536) + pool -> fp32 persist (32, 128, 256) [NBUF=3]
    conv_pool_mfma<128,256,32,64,2,2,false,3><<<dim3(128, 4), 256, 0, stream>>>(
        pooled2, sp[3], w3h, bp[3], didx[3], dwp[3], persist, 9, 7, 2);

    // FC1: (32,32768)@(32768,512), split-K partials then reduce+bias+ELU
    fc1_partial<<<dim3(4, 256), 256, 0, stream>>>(persist, Wl1, partial);
    fc1_reduce<<<64, 256, 0, stream>>>(partial, bl1, out);

    // FC2: (32,512)@(512,64) + bias -> d_out[16384:18432]
    fc2_kernel<<<32, 64, 0, stream>>>(out, Wl2, bl2, out + 16384);
}

// Round 8
// 269.238 us; speedup vs baseline: 1.1218x; 1.0541x over previous
//
#include <hip/hip_runtime.h>
#include <cstdint>
#include <cstddef>

typedef _Float16 f16x8 __attribute__((ext_vector_type(8)));
typedef _Float16 f16x4 __attribute__((ext_vector_type(4)));
typedef float f32x4 __attribute__((ext_vector_type(4)));

static __device__ __forceinline__ float elu_f(float t) {
    return t > 0.0f ? t : expm1f(t);
}

// async global->LDS 16B copy: per-lane GLOBAL source, linear LDS dest
// (wave-uniform base + lane*16).
typedef __attribute__((address_space(1))) const unsigned int guint;
typedef __attribute__((address_space(3))) unsigned int       luint;
static __device__ __forceinline__ void gload_lds16(const void* g, void* l)
{
    __builtin_amdgcn_global_load_lds((guint*)g, (luint*)l, 16, 0, 0);
}

// counted vmcnt wait (T4): literal immediates only, fenced per rule #18.
template<int N>
static __device__ __forceinline__ void vm_wait()
{
    static_assert(N == 0 || N == 4 || N == 5, "vmcnt literal");
    if constexpr (N == 0)      asm volatile("s_waitcnt vmcnt(0)" ::: "memory");
    else if constexpr (N == 4) asm volatile("s_waitcnt vmcnt(4)" ::: "memory");
    else                       asm volatile("s_waitcnt vmcnt(5)" ::: "memory");
    __builtin_amdgcn_sched_barrier(0);
}

// XCD-aware block -> pooled-vertex-tile remap (XCD = bid & 7 round-robin).
static __device__ __forceinline__ int block_pu0(int bid, int P, int vshift_out, int nbl)
{
    if (nbl < 0) return bid * P;
    int xcd  = bid & 7;
    int slot = bid >> 3;
    int nb   = slot & ((1 << nbl) - 1);
    int tile = slot >> nbl;
    return ((xcd + (nb << 3)) << vshift_out) + tile * P;
}

// ---------------- fused setup: weight prep + index prep + x transpose (1 dispatch) ----------------
template<int KTOT, int C_OUT, int BN>
static __device__ __forceinline__ void prep_w_body(const float* __restrict__ W,
                                                   _Float16* __restrict__ o, int i)
{
    constexpr int KT = KTOT/64;
    int j = i & 7;
    int rest = i >> 3;
    int n = rest % BN;
    int kc = (rest / BN) & 7;
    int t = (rest / (BN*8)) % KT;
    int y = rest / (BN*8*KT);
    int k = t*64 + kc*8 + j;
    o[i] = (_Float16)W[(size_t)k*C_OUT + y*BN + n];
}

__global__ __launch_bounds__(256)
void setup_all(const float* __restrict__ x0, _Float16* __restrict__ xT,
               const float* __restrict__ W0, const float* __restrict__ W1,
               const float* __restrict__ W2, const float* __restrict__ W3,
               const int* __restrict__ didx0, const int* __restrict__ spiral0,
               _Float16* __restrict__ w0h, _Float16* __restrict__ w1h,
               _Float16* __restrict__ w2h, _Float16* __restrict__ w3h,
               unsigned int* __restrict__ g)
{
    __shared__ _Float16 t[16][64*4 + 8];
    const int tid = threadIdx.x;
    int bid = blockIdx.x;

    if (bid < 1024) {
        // x transpose: (32,32768,3) fp32 -> 2x(32768,16,4) fp16
        const int h  = bid >> 9;
        const float* x = x0 + (size_t)h*16*98304;
        _Float16* xTh  = xT + (size_t)h*2097152;
        const int v0 = (bid & 511) * 64;
        #pragma unroll
        for (int it = 0; it < 4; ++it) {
            int e = it*256 + tid;          // 16 b x 64 v
            int b = e >> 6, v = e & 63;
            const float* p = x + ((size_t)b*32768 + v0 + v)*3;
            f16x4 hh;
            hh[0] = (_Float16)p[0]; hh[1] = (_Float16)p[1];
            hh[2] = (_Float16)p[2]; hh[3] = (_Float16)0.f;
            *(f16x4*)&t[b][v*4] = hh;
        }
        __syncthreads();
        #pragma unroll
        for (int it = 0; it < 2; ++it) {
            int e = it*256 + tid;          // 64 v x 8 s
            int vl = e >> 3, s = e & 7;
            f16x4 a = *(const f16x4*)&t[2*s][vl*4];
            f16x4 b = *(const f16x4*)&t[2*s+1][vl*4];
            f16x8 hh;
            hh[0]=a[0]; hh[1]=a[1]; hh[2]=a[2]; hh[3]=a[3];
            hh[4]=b[0]; hh[5]=b[1]; hh[6]=b[2]; hh[7]=b[3];
            *(f16x8*)&xTh[((size_t)(v0+vl)*16 + s*2)*4] = hh;
        }
        return;
    }
    bid -= 1024;

    if (bid < 8) {
        // level-0 weights: (36,32) -> padded K=64, k = s*4+c, tile [kc][n][8]
        int i = bid*256 + tid;                 // 2048
        int j = i & 7;
        int n = (i >> 3) & 31;
        int kc = i >> 8;
        int k = kc*8 + j;
        int s = k >> 2, c = k & 3;
        float v = (s < 12 && c < 3) ? W0[(size_t)(s*3 + c)*32 + n] : 0.0f;
        w0h[i] = (_Float16)v;
    } else if (bid < 104) {
        prep_w_body< 384,  64, 64>(W1, w1h, (bid - 8)*256 + tid);     // 24576
    } else if (bid < 488) {
        prep_w_body< 768, 128, 64>(W2, w2h, (bid - 104)*256 + tid);   // 98304
    } else if (bid < 2024) {
        prep_w_body<1536, 256, 64>(W3, w3h, (bid - 488)*256 + tid);   // 393216
    } else {
        // didx0 o spiral0 -> u16-pair table (24576 rows x 8)
        int i = (bid - 2024)*256 + tid;        // 196608
        int q = i & 7;
        int row = i >> 3;
        unsigned int val = 0;
        if (q < 6) {
            int v = didx0[row];
            unsigned int s0 = (unsigned int)spiral0[v*12 + q*2];
            unsigned int s1 = (unsigned int)spiral0[v*12 + q*2 + 1];
            val = s0 | (s1 << 16);
        }
        g[i] = val;
    }
}

// ---------------- conv0+pool0, both halves, batched-M over 16 batches ----------------
__global__ __launch_bounds__(256)
void conv0T(const _Float16* __restrict__ xT0, const unsigned int* __restrict__ gidx,
            const _Float16* __restrict__ Wp, const float* __restrict__ bias,
            const float* __restrict__ dwt, _Float16* __restrict__ out0)
{
    __shared__ _Float16 Ep[4][512];        // per-wave 1 KB transpose buffer
    const int h = blockIdx.x >> 10;
    const _Float16* xT = xT0 + (size_t)h*2097152;
    _Float16* out = out0 + (size_t)h*16*262144;
    const int tid  = threadIdx.x;
    const int wave = tid >> 6;
    const int lane = tid & 63;
    const int quad = lane >> 4;
    const int l16  = lane & 15;
    const int u0   = (blockIdx.x & 1023) * 8 + wave * 2;   // 2 u per wave

    f16x8 bf[2][2];
    #pragma unroll
    for (int kt = 0; kt < 2; ++kt)
        #pragma unroll
        for (int nt = 0; nt < 2; ++nt)
            bf[kt][nt] = *(const f16x8*)&Wp[(((kt*4+quad)*32) + nt*16 + l16)*8];
    float bv[2] = { bias[l16], bias[16 + l16] };

    #pragma unroll
    for (int ui = 0; ui < 2; ++ui) {
        int u = u0 + ui;
        f32x4 pacc[2] = {{0.f,0.f,0.f,0.f},{0.f,0.f,0.f,0.f}};
        #pragma unroll
        for (int kp = 0; kp < 3; ++kp) {
            int r = u*3 + kp;
            unsigned int gp0 = gidx[r*8 + quad];
            unsigned int gp1 = gidx[r*8 + 4 + quad];
            f16x4 a0 = *(const f16x4*)&xT[(size_t)(gp0 & 0xffffu)*64 + l16*4];
            f16x4 a1 = *(const f16x4*)&xT[(size_t)(gp0 >> 16)*64 + l16*4];
            f16x4 a2 = *(const f16x4*)&xT[(size_t)(gp1 & 0xffffu)*64 + l16*4];
            f16x4 a3 = *(const f16x4*)&xT[(size_t)(gp1 >> 16)*64 + l16*4];
            f16x8 af0, af1;
            af0[0]=a0[0]; af0[1]=a0[1]; af0[2]=a0[2]; af0[3]=a0[3];
            af0[4]=a1[0]; af0[5]=a1[1]; af0[6]=a1[2]; af0[7]=a1[3];
            af1[0]=a2[0]; af1[1]=a2[1]; af1[2]=a2[2]; af1[3]=a2[3];
            af1[4]=a3[0]; af1[5]=a3[1]; af1[6]=a3[2]; af1[7]=a3[3];
            float dw = dwt[r];
            #pragma unroll
            for (int nt = 0; nt < 2; ++nt) {
                f32x4 m = {0.f,0.f,0.f,0.f};
                m = __builtin_amdgcn_mfma_f32_16x16x32_f16(af0, bf[0][nt], m, 0,0,0);
                m = __builtin_amdgcn_mfma_f32_16x16x32_f16(af1, bf[1][nt], m, 0,0,0);
                #pragma unroll
                for (int rr = 0; rr < 4; ++rr)
                    pacc[nt][rr] += dw * elu_f(m[rr] + bv[nt]);
            }
        }
        #pragma unroll
        for (int nt = 0; nt < 2; ++nt)
            #pragma unroll
            for (int rr = 0; rr < 4; ++rr)
                Ep[wave][(quad*4+rr)*32 + nt*16 + l16] = (_Float16)pacc[nt][rr];
        int b  = lane >> 2;
        int c8 = lane & 3;
        f16x8 rowv = *(const f16x8*)&Ep[wave][b*32 + c8*8];
        *(f16x8*)&out[(size_t)b*262144 + (size_t)u*32 + c8*8] = rowv;
    }
}

// ---------------- fused conv+pool: multi-buffer LDS staging, COUNTED vmcnt ----------------
// Per-level NBUF: L1 uses NBUF=2 (depth-1 counted wait, 37.4KB, 4 blocks/CU);
// L2/L3 keep NBUF=3 (depth-2, 2 blocks/CU, measured better than drain-0).
// Ledger: the K-loop's only VMEM ops are the stage's own LPW loads; pre-loop
// gather loads are drained by the __syncthreads after gidx staging.
// MFMA order per K-step unchanged -> identical numerics.
template<int C_IN, int C_OUT, int P, int BN, int WGM, int WGN, bool OUT_HALF, int NBUF>
__global__ __launch_bounds__(256)
void conv_pool_mfma(const _Float16* __restrict__ x, const int* __restrict__ spiral,
                    const _Float16* __restrict__ Wp, const float* __restrict__ bias,
                    const int* __restrict__ didx, const float* __restrict__ dwt,
                    void* __restrict__ outv, int vshift_in, int vshift_out, int nbl)
{
    constexpr int R    = 3*P;
    constexpr int KTOT = 12*C_IN;
    constexpr int KT   = KTOT/64;
    constexpr int NST  = KT*2;           // number of K=32 steps
    constexpr int WTM  = R/WGM;
    constexpr int WTN  = BN/WGN;
    constexpr int NMT  = WTM/16;
    constexpr int NNT  = WTN/16;
    constexpr int C4   = BN/4;
    constexpr int GS   = (C_IN == 32) ? 1 : 2;   // K-steps per staging group
    constexpr int NG   = NST / GS;
    constexpr int CPR  = GS * 4;         // 16B chunks per staged row-part (4 or 8)
    constexpr int CPRS = (CPR == 4) ? 2 : 3;
    constexpr int ACH  = R * CPR;        // A chunks per group
    constexpr int BCH  = GS * BN * 4;    // B chunks per group
    constexpr int AIPW = ACH / 256;      // global_load_lds instrs per wave
    constexpr int BIPW = BCH / 256;
    constexpr int LPW  = AIPW + BIPW;    // own loads per stage (vmcnt unit)
    constexpr int ASUBH = R * GS * 32;   // halfs per A sub-buffer
    constexpr int BSUBH = GS * 32 * BN;  // halfs per B sub-buffer
    static_assert(WTM % 16 == 0 && WTN % 16 == 0, "tile");
    static_assert(R <= 256 && (P*C4) % 256 == 0, "loops");
    static_assert(ACH % 256 == 0 && BCH % 256 == 0, "stage");
    static_assert(NST % GS == 0 && GS*32 <= C_IN, "group");
    static_assert(NBUF == 2 || NBUF == 3, "nbuf");
    static_assert(NBUF == 2 ? NG >= 2 : NG >= 3, "pipeline depth");

    constexpr size_t BUFB = (size_t)(NBUF*(ASUBH + BSUBH)) * 2;
    constexpr size_t EB   = (size_t)R * (BN + 4) * 2;
    constexpr size_t GOFF = (BUFB > EB ? BUFB : EB);
    static_assert(GOFF + (size_t)R*12*2 <= 65536, "LDS budget");
    __shared__ __align__(16) char smem[GOFF + (size_t)R*12*2];
    _Float16* Ab = (_Float16*)smem;
    _Float16* Bb = (_Float16*)(smem + (size_t)NBUF*ASUBH*2);
    unsigned short* gidx = (unsigned short*)(smem + GOFF);
    _Float16* E = (_Float16*)smem;       // overlays staging bufs (dead after K-loop)

    const int tid  = threadIdx.x;
    const int wave = tid >> 6;
    const int lane = tid & 63;
    const int quad = lane >> 4;
    const int l16  = lane & 15;
    const int wm   = wave / WGN;
    const int wn   = wave % WGN;
    const int pu0  = block_pu0(blockIdx.x, P, vshift_out, nbl);
    const int n0   = blockIdx.y * BN;
    const int vmask_out = (1 << vshift_out) - 1;
    const int base_in = (pu0 >> vshift_out) << vshift_in;

    if (tid < R) {
        int ul = tid / 3;
        int kp = tid - ul*3;
        int u  = (pu0 + ul) & vmask_out;
        int v  = didx[u*3 + kp];
        const int* svp = spiral + v*12;
        #pragma unroll
        for (int j = 0; j < 12; ++j) gidx[tid*12 + j] = (unsigned short)svp[j];
    }
    __syncthreads();   // also drains the gather loads above (vmcnt ledger reset)

    f32x4 acc[NMT][NNT];
    #pragma unroll
    for (int i = 0; i < NMT; ++i)
        #pragma unroll
        for (int j = 0; j < NNT; ++j) acc[i][j] = (f32x4){0.f, 0.f, 0.f, 0.f};

    const _Float16* xb = x + (size_t)base_in * C_IN;

    // chunk swizzle: slot q of row r holds global chunk q ^ SWZ(r)
    auto SWZ = [](int r) -> int {
        return (CPR == 4) ? ((r & 3) ^ ((r >> 2) & 3)) : (r & 7);
    };

    auto stage = [&](int g, int buf) {
        const int k0g = g * GS * 32;
        const int sv  = k0g / C_IN;
        const int c0  = k0g % C_IN;                  // halfs
        _Float16* Ad = Ab + (size_t)buf * ASUBH;
        #pragma unroll
        for (int i = 0; i < AIPW; ++i) {
            int t  = (wave*AIPW + i)*64 + lane;
            int r  = t >> CPRS;
            int q  = t & (CPR - 1);
            int qq = q ^ SWZ(r);
            int gr = gidx[r*12 + sv];
            gload_lds16(xb + (size_t)gr*C_IN + c0 + qq*8,
                        Ad + (size_t)(wave*AIPW + i)*512);
        }
        _Float16* Bd = Bb + (size_t)buf * BSUBH;
        const _Float16* bs = Wp + ((size_t)(blockIdx.y*NST + g*GS)*4)*BN*8;
        #pragma unroll
        for (int i = 0; i < BIPW; ++i) {
            int t = (wave*BIPW + i)*64 + lane;
            gload_lds16(bs + (size_t)t*8,
                        Bd + (size_t)(wave*BIPW + i)*512);
        }
    };

    auto compute = [&](int cb) {
        const _Float16* Ar = Ab + (size_t)cb * ASUBH;
        const _Float16* Br = Bb + (size_t)cb * BSUBH;
        #pragma unroll
        for (int sl = 0; sl < GS; ++sl) {
            f16x8 af[NMT], bf[NNT];
            #pragma unroll
            for (int i = 0; i < NMT; ++i) {
                int m = wm*WTM + i*16 + l16;
                af[i] = *(const f16x8*)&Ar[(size_t)(m*CPR + ((sl*4 + quad) ^ SWZ(m)))*8];
            }
            #pragma unroll
            for (int j = 0; j < NNT; ++j) {
                int n = wn*WTN + j*16 + l16;
                bf[j] = *(const f16x8*)&Br[(size_t)((sl*4 + quad)*BN + n)*8];
            }
            #pragma unroll
            for (int i = 0; i < NMT; ++i)
                #pragma unroll
                for (int j = 0; j < NNT; ++j)
                    acc[i][j] = __builtin_amdgcn_mfma_f32_16x16x32_f16(
                        af[i], bf[j], acc[i][j], 0, 0, 0);
        }
    };

    if constexpr (NBUF == 3) {
        stage(0, 0);
        stage(1, 1);
        int cur = 0;
        for (int g = 0; g < NG; ++g) {
            if (g + 1 < NG) vm_wait<LPW>(); else vm_wait<0>();
            __builtin_amdgcn_s_barrier();
            __builtin_amdgcn_sched_barrier(0);
            int nx2 = cur + 2; if (nx2 >= 3) nx2 -= 3;
            if (g + 2 < NG) stage(g + 2, nx2);
            compute(cur);
            asm volatile("s_waitcnt lgkmcnt(0)" ::: "memory");
            __builtin_amdgcn_sched_barrier(0);
            __builtin_amdgcn_s_barrier();
            __builtin_amdgcn_sched_barrier(0);
            cur = (cur + 1 == 3) ? 0 : cur + 1;
        }
    } else {
        stage(0, 0);
        int cur = 0;
        for (int g = 0; g < NG; ++g) {
            if (g + 1 < NG) {
                stage(g + 1, cur ^ 1);   // buf cur^1's readers done at g-1 bottom
                vm_wait<LPW>();          // stage g landed, g+1 stays in flight
            } else {
                vm_wait<0>();
            }
            __builtin_amdgcn_s_barrier();
            __builtin_amdgcn_sched_barrier(0);
            compute(cur);
            asm volatile("s_waitcnt lgkmcnt(0)" ::: "memory");
            __builtin_amdgcn_sched_barrier(0);
            __builtin_amdgcn_s_barrier();
            __builtin_amdgcn_sched_barrier(0);
            cur ^= 1;
        }
    }

    float bv[NNT];
    #pragma unroll
    for (int j = 0; j < NNT; ++j)
        bv[j] = bias[n0 + wn*WTN + j*16 + l16];

    #pragma unroll
    for (int i = 0; i < NMT; ++i) {
        int row_base = wm*WTM + i*16 + quad*4;
        #pragma unroll
        for (int j = 0; j < NNT; ++j) {
            int col = wn*WTN + j*16 + l16;
            #pragma unroll
            for (int r = 0; r < 4; ++r)
                E[(size_t)(row_base + r)*(BN+4) + col] =
                    (_Float16)elu_f(acc[i][j][r] + bv[j]);
        }
    }
    __syncthreads();

    #pragma unroll
    for (int e = tid; e < P*C4; e += 256) {
        int ul = e / C4;
        int c4 = e - ul*C4;
        int pu = pu0 + ul;
        int u  = pu & vmask_out;
        const float* w = dwt + u*3;
        f16x4 a0 = *(const f16x4*)&E[(size_t)(ul*3 + 0)*(BN+4) + c4*4];
        f16x4 a1 = *(const f16x4*)&E[(size_t)(ul*3 + 1)*(BN+4) + c4*4];
        f16x4 a2 = *(const f16x4*)&E[(size_t)(ul*3 + 2)*(BN+4) + c4*4];
        float ox = w[0]*(float)a0[0] + w[1]*(float)a1[0] + w[2]*(float)a2[0];
        float oy = w[0]*(float)a0[1] + w[1]*(float)a1[1] + w[2]*(float)a2[1];
        float oz = w[0]*(float)a0[2] + w[1]*(float)a1[2] + w[2]*(float)a2[2];
        float ow = w[0]*(float)a0[3] + w[1]*(float)a1[3] + w[2]*(float)a2[3];
        if (OUT_HALF) {
            f16x4 h; h[0]=(_Float16)ox; h[1]=(_Float16)oy; h[2]=(_Float16)oz; h[3]=(_Float16)ow;
            *(f16x4*)&((_Float16*)outv)[(size_t)pu*C_OUT + n0 + c4*4] = h;
        } else {
            float4 o; o.x=ox; o.y=oy; o.z=oz; o.w=ow;
            *(float4*)&((float*)outv)[(size_t)pu*C_OUT + n0 + c4*4] = o;
        }
    }
}

// ---------------- FC1: atomic-free split-K (ks=256, k-chunk 128) ----------------
__global__ __launch_bounds__(256)
void fc1_partial(const float* __restrict__ xflat, const float* __restrict__ Wl1,
                 float* __restrict__ partial)
{
    __shared__ float sb[8704];
    const int tid = threadIdx.x;
    const int n4 = tid & 31;
    const int kq = (tid >> 5) & 3;
    const int mh = tid >> 7;
    const int nt = blockIdx.x;
    const int ks = blockIdx.y;
    const int kbase = ks * 128;

    for (int e = tid; e < 1024; e += 256) {
        int m = e >> 5, k4 = e & 31;
        *(float4*)&sb[m*128 + k4*4] = *(const float4*)&xflat[(size_t)m*32768 + kbase + k4*4];
    }
    __syncthreads();

    float acc[16][4];
    #pragma unroll
    for (int m = 0; m < 16; ++m)
        #pragma unroll
        for (int c = 0; c < 4; ++c) acc[m][c] = 0.0f;

    const float* Wb = Wl1 + (size_t)(kbase + kq*32)*512 + nt*128 + n4*4;
    #pragma unroll 2
    for (int i = 0; i < 32; i += 4) {
        float4 w0 = *(const float4*)(Wb + (size_t)(i+0)*512);
        float4 w1 = *(const float4*)(Wb + (size_t)(i+1)*512);
        float4 w2 = *(const float4*)(Wb + (size_t)(i+2)*512);
        float4 w3 = *(const float4*)(Wb + (size_t)(i+3)*512);
        #pragma unroll
        for (int m = 0; m < 16; ++m) {
            float4 xv = *(const float4*)&sb[(mh*16 + m)*128 + kq*32 + i];
            acc[m][0] += xv.x*w0.x + xv.y*w1.x + xv.z*w2.x + xv.w*w3.x;
            acc[m][1] += xv.x*w0.y + xv.y*w1.y + xv.z*w2.y + xv.w*w3.y;
            acc[m][2] += xv.x*w0.z + xv.y*w1.z + xv.z*w2.z + xv.w*w3.z;
            acc[m][3] += xv.x*w0.w + xv.y*w1.w + xv.z*w2.w + xv.w*w3.w;
        }
    }
    __syncthreads();

    int slot = (mh*2 + (kq >> 1))*32 + n4;
    if (kq & 1) {
        #pragma unroll
        for (int m = 0; m < 16; ++m)
            *(float4*)&sb[slot*68 + m*4] = *(float4*)&acc[m][0];
    }
    __syncthreads();
    if (!(kq & 1)) {
        #pragma unroll
        for (int m = 0; m < 16; ++m) {
            float4 v = *(const float4*)&sb[slot*68 + m*4];
            acc[m][0] += v.x; acc[m][1] += v.y; acc[m][2] += v.z; acc[m][3] += v.w;
        }
    }
    __syncthreads();
    int slot2 = mh*32 + n4;
    if (kq == 2) {
        #pragma unroll
        for (int m = 0; m < 16; ++m)
            *(float4*)&sb[slot2*68 + m*4] = *(float4*)&acc[m][0];
    }
    __syncthreads();
    if (kq == 0) {
        float* pb = partial + ((size_t)(ks*4 + nt)*32 + mh*16)*128 + n4*4;
        #pragma unroll
        for (int m = 0; m < 16; ++m) {
            float4 v = *(const float4*)&sb[slot2*68 + m*4];
            float4 o;
            o.x = acc[m][0] + v.x; o.y = acc[m][1] + v.y;
            o.z = acc[m][2] + v.z; o.w = acc[m][3] + v.w;
            *(float4*)(pb + (size_t)m*128) = o;
        }
    }
}

// ---------------- FC1 reduce + ELU + FC2, fused (one block per batch row m) ----------------
// Saves a dispatch node plus the hout HBM round-trip (hout kept in LDS for fc2).
// fc1 sum order (ks 0..255 serial) unchanged; fc2's 512-dot is chunked 8x64
// (last-bit-only change in y, absmax dominated by fp16 conv path).
__global__ __launch_bounds__(512)
void fc1_finish(const float* __restrict__ partial, const float* __restrict__ bl1,
                const float* __restrict__ Wl2, const float* __restrict__ bl2,
                float* __restrict__ out)
{
    __shared__ float hh[512];
    __shared__ float ps[512];
    const int m = blockIdx.x;
    const int tid = threadIdx.x;
    const int nt = tid >> 7, nl = tid & 127;

    const float* p = partial + ((size_t)nt*32 + m)*128 + nl;
    float s = 0.0f;
    #pragma unroll 8
    for (int ks = 0; ks < 256; ++ks)
        s += p[(size_t)ks*16384];
    float h = elu_f(s + bl1[tid]);
    out[(size_t)m*512 + tid] = h;      // hout output
    hh[tid] = h;
    __syncthreads();

    // fc2: y[m][c] = bl2[c] + sum_k hh[k]*Wl2[k*64+c]
    const int c  = tid & 63;
    const int kc = tid >> 6;
    float a = 0.0f;
    #pragma unroll 8
    for (int k = kc*64; k < kc*64 + 64; ++k)
        a += hh[k] * Wl2[(size_t)k*64 + c];
    ps[tid] = a;
    __syncthreads();
    if (tid < 64) {
        float y = bl2[tid];
        #pragma unroll
        for (int j = 0; j < 8; ++j) y += ps[j*64 + tid];
        out[16384 + (size_t)m*64 + tid] = y;
    }
}

extern "C" void kernel_launch(void* const* d_in, const int* in_sizes, int n_in,
                              void* d_out, int out_size, void* d_ws, size_t ws_size,
                              hipStream_t stream)
{
    (void)in_sizes; (void)n_in; (void)out_size; (void)ws_size;

    const float* x0 = (const float*)d_in[0];
    const int*   sp[4]; const int* didx[4]; const float* dwp[4];
    const float* Wp[4]; const float* bp[4];
    for (int i = 0; i < 4; ++i) {
        sp[i]   = (const int*)  d_in[1 + i*5 + 0];
        didx[i] = (const int*)  d_in[1 + i*5 + 1];
        dwp[i]  = (const float*)d_in[1 + i*5 + 2];
        Wp[i]   = (const float*)d_in[1 + i*5 + 3];
        bp[i]   = (const float*)d_in[1 + i*5 + 4];
    }
    const float* Wl1 = (const float*)d_in[21];
    const float* bl1 = (const float*)d_in[22];
    const float* Wl2 = (const float*)d_in[23];
    const float* bl2 = (const float*)d_in[24];
    float* out = (float*)d_out;

    char* wsb = (char*)d_ws;
    float* persist      = (float*)wsb;                    // 4 MB   (32,128,256) fp32
    float* partial      = (float*)(wsb + (4<<20));        // 16.8 MB (1024 x 4096 f32)
    _Float16* xT        = (_Float16*)(wsb + (24<<20));    // 8 MB   (2 halves x 4 MB)
    _Float16* pooled0   = (_Float16*)(wsb + (32<<20));    // 16 MB  (32,8192,32) fp16
    _Float16* pooled1   = (_Float16*)(wsb + (48<<20));    // 8 MB   (32,2048,64) fp16
    _Float16* pooled2   = (_Float16*)(wsb + (56<<20));    // 4 MB   (32,512,128) fp16
    unsigned int* gidx0 = (unsigned int*)(wsb + (60<<20));// 0.75 MB
    _Float16* w0h       = (_Float16*)(wsb + (61<<20));
    _Float16* w1h       = w0h + 2048;
    _Float16* w2h       = w1h + 24576;
    _Float16* w3h       = w2h + 98304;

    // setup: x transpose + all weight/index prep in ONE dispatch
    setup_all<<<3816, 256, 0, stream>>>(x0, xT,
                                        Wp[0], Wp[1], Wp[2], Wp[3],
                                        didx[0], sp[0],
                                        w0h, w1h, w2h, w3h, gidx0);

    // L0: conv0 (both halves, 1 dispatch)
    conv0T<<<2048, 256, 0, stream>>>(xT, gidx0, w0h, bp[0], dwp[0], pooled0);

    // L1: conv(32->64, K=384) + pool -> fp16 (32, 2048, 64)
    //     NBUF=2 counted (37.4KB LDS -> 4 blocks/CU)
    conv_pool_mfma<32,64,64,64,4,1,true,2><<<1024, 256, 0, stream>>>(
        pooled0, sp[1], w1h, bp[1], didx[1], dwp[1], pooled1, 13, 11, 2);

    // L2: conv(64->128, K=768) + pool -> fp16 (32, 512, 128)  [NBUF=3 depth-2]
    conv_pool_mfma<64,128,32,64,2,2,true,3><<<dim3(512, 2), 256, 0, stream>>>(
        pooled1, sp[2], w2h, bp[2], didx[2], dwp[2], pooled2, 11, 9, 2);

    // L3: conv(128->256, K=1536) + pool -> fp32 persist (32, 128, 256) [NBUF=3]
    conv_pool_mfma<128,256,32,64,2,2,false,3><<<dim3(128, 4), 256, 0, stream>>>(
        pooled2, sp[3], w3h, bp[3], didx[3], dwp[3], persist, 9, 7, 2);

    // FC1: (32,32768)@(32768,512), split-K partials then fused reduce+ELU+FC2
    fc1_partial<<<dim3(4, 256), 256, 0, stream>>>(persist, Wl1, partial);
    fc1_finish<<<32, 512, 0, stream>>>(partial, bl1, Wl2, bl2, out);
}

// Round 9
// 266.374 us; speedup vs baseline: 1.1339x; 1.0108x over previous
//
#include <hip/hip_runtime.h>
#include <cstdint>
#include <cstddef>

typedef _Float16 f16x8 __attribute__((ext_vector_type(8)));
typedef _Float16 f16x4 __attribute__((ext_vector_type(4)));
typedef float f32x4 __attribute__((ext_vector_type(4)));

static __device__ __forceinline__ float elu_f(float t) {
    return t > 0.0f ? t : expm1f(t);
}

// async global->LDS 16B copy: per-lane GLOBAL source, linear LDS dest
// (wave-uniform base + lane*16).
typedef __attribute__((address_space(1))) const unsigned int guint;
typedef __attribute__((address_space(3))) unsigned int       luint;
static __device__ __forceinline__ void gload_lds16(const void* g, void* l)
{
    __builtin_amdgcn_global_load_lds((guint*)g, (luint*)l, 16, 0, 0);
}

// counted vmcnt wait (T4): literal immediates only, fenced per rule #18.
template<int N>
static __device__ __forceinline__ void vm_wait()
{
    static_assert(N == 0 || N == 4 || N == 5 || N == 7, "vmcnt literal");
    if constexpr (N == 0)      asm volatile("s_waitcnt vmcnt(0)" ::: "memory");
    else if constexpr (N == 4) asm volatile("s_waitcnt vmcnt(4)" ::: "memory");
    else if constexpr (N == 5) asm volatile("s_waitcnt vmcnt(5)" ::: "memory");
    else                       asm volatile("s_waitcnt vmcnt(7)" ::: "memory");
    __builtin_amdgcn_sched_barrier(0);
}

// XCD-aware block -> pooled-vertex-tile remap (XCD = bid & 7 round-robin).
static __device__ __forceinline__ int block_pu0(int bid, int P, int vshift_out, int nbl)
{
    if (nbl < 0) return bid * P;
    int xcd  = bid & 7;
    int slot = bid >> 3;
    int nb   = slot & ((1 << nbl) - 1);
    int tile = slot >> nbl;
    return ((xcd + (nb << 3)) << vshift_out) + tile * P;
}

// ---------------- fused setup: weight prep + index prep + x transpose (1 dispatch) ----------------
template<int KTOT, int C_OUT, int BN>
static __device__ __forceinline__ void prep_w_body(const float* __restrict__ W,
                                                   _Float16* __restrict__ o, int i)
{
    constexpr int KT = KTOT/64;
    int j = i & 7;
    int rest = i >> 3;
    int n = rest % BN;
    int kc = (rest / BN) & 7;
    int t = (rest / (BN*8)) % KT;
    int y = rest / (BN*8*KT);
    int k = t*64 + kc*8 + j;
    o[i] = (_Float16)W[(size_t)k*C_OUT + y*BN + n];
}

__global__ __launch_bounds__(256)
void setup_all(const float* __restrict__ x0, _Float16* __restrict__ xT,
               const float* __restrict__ W0, const float* __restrict__ W1,
               const float* __restrict__ W2, const float* __restrict__ W3,
               const int* __restrict__ didx0, const int* __restrict__ spiral0,
               _Float16* __restrict__ w0h, _Float16* __restrict__ w1h,
               _Float16* __restrict__ w2h, _Float16* __restrict__ w3h,
               unsigned int* __restrict__ g)
{
    __shared__ _Float16 t[16][64*4 + 8];
    const int tid = threadIdx.x;
    int bid = blockIdx.x;

    if (bid < 1024) {
        // x transpose: (32,32768,3) fp32 -> 2x(32768,16,4) fp16
        const int h  = bid >> 9;
        const float* x = x0 + (size_t)h*16*98304;
        _Float16* xTh  = xT + (size_t)h*2097152;
        const int v0 = (bid & 511) * 64;
        #pragma unroll
        for (int it = 0; it < 4; ++it) {
            int e = it*256 + tid;          // 16 b x 64 v
            int b = e >> 6, v = e & 63;
            const float* p = x + ((size_t)b*32768 + v0 + v)*3;
            f16x4 hh;
            hh[0] = (_Float16)p[0]; hh[1] = (_Float16)p[1];
            hh[2] = (_Float16)p[2]; hh[3] = (_Float16)0.f;
            *(f16x4*)&t[b][v*4] = hh;
        }
        __syncthreads();
        #pragma unroll
        for (int it = 0; it < 2; ++it) {
            int e = it*256 + tid;          // 64 v x 8 s
            int vl = e >> 3, s = e & 7;
            f16x4 a = *(const f16x4*)&t[2*s][vl*4];
            f16x4 b = *(const f16x4*)&t[2*s+1][vl*4];
            f16x8 hh;
            hh[0]=a[0]; hh[1]=a[1]; hh[2]=a[2]; hh[3]=a[3];
            hh[4]=b[0]; hh[5]=b[1]; hh[6]=b[2]; hh[7]=b[3];
            *(f16x8*)&xTh[((size_t)(v0+vl)*16 + s*2)*4] = hh;
        }
        return;
    }
    bid -= 1024;

    if (bid < 8) {
        // level-0 weights: (36,32) -> padded K=64, k = s*4+c, tile [kc][n][8]
        int i = bid*256 + tid;                 // 2048
        int j = i & 7;
        int n = (i >> 3) & 31;
        int kc = i >> 8;
        int k = kc*8 + j;
        int s = k >> 2, c = k & 3;
        float v = (s < 12 && c < 3) ? W0[(size_t)(s*3 + c)*32 + n] : 0.0f;
        w0h[i] = (_Float16)v;
    } else if (bid < 104) {
        prep_w_body< 384,  64, 64>(W1, w1h, (bid - 8)*256 + tid);     // 24576
    } else if (bid < 488) {
        prep_w_body< 768, 128, 64>(W2, w2h, (bid - 104)*256 + tid);   // 98304
    } else if (bid < 2024) {
        prep_w_body<1536, 256, 64>(W3, w3h, (bid - 488)*256 + tid);   // 393216
    } else {
        // didx0 o spiral0 -> u16-pair table (24576 rows x 8)
        int i = (bid - 2024)*256 + tid;        // 196608
        int q = i & 7;
        int row = i >> 3;
        unsigned int val = 0;
        if (q < 6) {
            int v = didx0[row];
            unsigned int s0 = (unsigned int)spiral0[v*12 + q*2];
            unsigned int s1 = (unsigned int)spiral0[v*12 + q*2 + 1];
            val = s0 | (s1 << 16);
        }
        g[i] = val;
    }
}

// ---------------- conv0+pool0, both halves, batched-M over 16 batches ----------------
__global__ __launch_bounds__(256)
void conv0T(const _Float16* __restrict__ xT0, const unsigned int* __restrict__ gidx,
            const _Float16* __restrict__ Wp, const float* __restrict__ bias,
            const float* __restrict__ dwt, _Float16* __restrict__ out0)
{
    __shared__ _Float16 Ep[4][512];        // per-wave 1 KB transpose buffer
    const int h = blockIdx.x >> 10;
    const _Float16* xT = xT0 + (size_t)h*2097152;
    _Float16* out = out0 + (size_t)h*16*262144;
    const int tid  = threadIdx.x;
    const int wave = tid >> 6;
    const int lane = tid & 63;
    const int quad = lane >> 4;
    const int l16  = lane & 15;
    const int u0   = (blockIdx.x & 1023) * 8 + wave * 2;   // 2 u per wave

    f16x8 bf[2][2];
    #pragma unroll
    for (int kt = 0; kt < 2; ++kt)
        #pragma unroll
        for (int nt = 0; nt < 2; ++nt)
            bf[kt][nt] = *(const f16x8*)&Wp[(((kt*4+quad)*32) + nt*16 + l16)*8];
    float bv[2] = { bias[l16], bias[16 + l16] };

    #pragma unroll
    for (int ui = 0; ui < 2; ++ui) {
        int u = u0 + ui;
        f32x4 pacc[2] = {{0.f,0.f,0.f,0.f},{0.f,0.f,0.f,0.f}};
        #pragma unroll
        for (int kp = 0; kp < 3; ++kp) {
            int r = u*3 + kp;
            unsigned int gp0 = gidx[r*8 + quad];
            unsigned int gp1 = gidx[r*8 + 4 + quad];
            f16x4 a0 = *(const f16x4*)&xT[(size_t)(gp0 & 0xffffu)*64 + l16*4];
            f16x4 a1 = *(const f16x4*)&xT[(size_t)(gp0 >> 16)*64 + l16*4];
            f16x4 a2 = *(const f16x4*)&xT[(size_t)(gp1 & 0xffffu)*64 + l16*4];
            f16x4 a3 = *(const f16x4*)&xT[(size_t)(gp1 >> 16)*64 + l16*4];
            f16x8 af0, af1;
            af0[0]=a0[0]; af0[1]=a0[1]; af0[2]=a0[2]; af0[3]=a0[3];
            af0[4]=a1[0]; af0[5]=a1[1]; af0[6]=a1[2]; af0[7]=a1[3];
            af1[0]=a2[0]; af1[1]=a2[1]; af1[2]=a2[2]; af1[3]=a2[3];
            af1[4]=a3[0]; af1[5]=a3[1]; af1[6]=a3[2]; af1[7]=a3[3];
            float dw = dwt[r];
            #pragma unroll
            for (int nt = 0; nt < 2; ++nt) {
                f32x4 m = {0.f,0.f,0.f,0.f};
                m = __builtin_amdgcn_mfma_f32_16x16x32_f16(af0, bf[0][nt], m, 0,0,0);
                m = __builtin_amdgcn_mfma_f32_16x16x32_f16(af1, bf[1][nt], m, 0,0,0);
                #pragma unroll
                for (int rr = 0; rr < 4; ++rr)
                    pacc[nt][rr] += dw * elu_f(m[rr] + bv[nt]);
            }
        }
        #pragma unroll
        for (int nt = 0; nt < 2; ++nt)
            #pragma unroll
            for (int rr = 0; rr < 4; ++rr)
                Ep[wave][(quad*4+rr)*32 + nt*16 + l16] = (_Float16)pacc[nt][rr];
        int b  = lane >> 2;
        int c8 = lane & 3;
        f16x8 rowv = *(const f16x8*)&Ep[wave][b*32 + c8*8];
        *(f16x8*)&out[(size_t)b*262144 + (size_t)u*32 + c8*8] = rowv;
    }
}

// ---------------- fused conv+pool: A-only LDS staging + register B (BREG) ----------------
// Round-9 change: B-tile addresses are REGULAR (no gidx dependency) and
// L2-resident, so B moves out of LDS into double-buffered registers prefetched
// one group ahead. LDS drops 59.9 -> 38.3KB => L2 level goes 2 -> 4 blocks/CU
// (grid 1024), and each K-step loses 2 of 5 ds_reads. vmcnt ledger (in-order
// retirement, m135): per group issue stageA(g+2)[AIPW] + loadB(g+1)[NB], then
// vm_wait<AIPW+NB> retires exactly A(g+1)+B(g) -- the operands compute(g)
// needs -- while A(g+2)+B(g+1) stay in flight. sched_barrier(0) fences stop
// the scheduler sinking the B register loads (rounds-0-3 failure mode).
// L1 keeps the proven !BREG path (its B-reg variant would blow the VGPR
// budget at 4 blocks/CU). MFMA operand values and order unchanged.
template<int C_IN, int C_OUT, int P, int BN, int WGM, int WGN, bool OUT_HALF, int NBUF, bool BREG>
__global__ __launch_bounds__(256)
void conv_pool_mfma(const _Float16* __restrict__ x, const int* __restrict__ spiral,
                    const _Float16* __restrict__ Wp, const float* __restrict__ bias,
                    const int* __restrict__ didx, const float* __restrict__ dwt,
                    void* __restrict__ outv, int vshift_in, int vshift_out, int nbl)
{
    constexpr int R    = 3*P;
    constexpr int KTOT = 12*C_IN;
    constexpr int KT   = KTOT/64;
    constexpr int NST  = KT*2;           // number of K=32 steps
    constexpr int WTM  = R/WGM;
    constexpr int WTN  = BN/WGN;
    constexpr int NMT  = WTM/16;
    constexpr int NNT  = WTN/16;
    constexpr int C4   = BN/4;
    constexpr int GS   = (C_IN == 32) ? 1 : 2;   // K-steps per staging group
    constexpr int NG   = NST / GS;
    constexpr int CPR  = GS * 4;         // 16B chunks per staged row-part (4 or 8)
    constexpr int CPRS = (CPR == 4) ? 2 : 3;
    constexpr int ACH  = R * CPR;        // A chunks per group
    constexpr int BCH  = GS * BN * 4;    // B chunks per group (!BREG only)
    constexpr int AIPW = ACH / 256;      // global_load_lds instrs per wave
    constexpr int BIPW = BCH / 256;
    constexpr int LPW  = AIPW + BIPW;    // !BREG: own loads per stage
    constexpr int NB   = GS * NNT;       // BREG: B register loads per group
    constexpr int FULLW = AIPW + NB;     // BREG steady-state vmcnt
    constexpr int ASUBH = R * GS * 32;   // halfs per A sub-buffer
    constexpr int BSUBH = GS * 32 * BN;  // halfs per B sub-buffer (!BREG)
    static_assert(WTM % 16 == 0 && WTN % 16 == 0, "tile");
    static_assert(R <= 256 && (P*C4) % 256 == 0, "loops");
    static_assert(ACH % 256 == 0, "stageA");
    static_assert(BREG || BCH % 256 == 0, "stageB");
    static_assert(NST % GS == 0 && GS*32 <= C_IN, "group");
    static_assert(NBUF == 2 || NBUF == 3, "nbuf");
    static_assert(!BREG || (NBUF == 3 && NG % 2 == 0 && NG >= 4), "breg pipeline");
    static_assert(BREG || (NBUF == 2 ? NG >= 2 : NG >= 3), "pipeline depth");

    constexpr size_t BUFB = (BREG ? (size_t)NBUF*ASUBH
                                  : (size_t)NBUF*(ASUBH + BSUBH)) * 2;
    constexpr size_t EB   = (size_t)R * (BN + 4) * 2;
    constexpr size_t GOFF = (BUFB > EB ? BUFB : EB);
    static_assert(GOFF + (size_t)R*12*2 <= 65536, "LDS budget");
    __shared__ __align__(16) char smem[GOFF + (size_t)R*12*2];
    _Float16* Ab = (_Float16*)smem;
    _Float16* Bb = (_Float16*)(smem + (size_t)NBUF*ASUBH*2);   // !BREG only
    unsigned short* gidx = (unsigned short*)(smem + GOFF);
    _Float16* E = (_Float16*)smem;       // overlays staging bufs (dead after K-loop)

    const int tid  = threadIdx.x;
    const int wave = tid >> 6;
    const int lane = tid & 63;
    const int quad = lane >> 4;
    const int l16  = lane & 15;
    const int wm   = wave / WGN;
    const int wn   = wave % WGN;
    const int pu0  = block_pu0(blockIdx.x, P, vshift_out, nbl);
    const int n0   = blockIdx.y * BN;
    const int vmask_out = (1 << vshift_out) - 1;
    const int base_in = (pu0 >> vshift_out) << vshift_in;

    if (tid < R) {
        int ul = tid / 3;
        int kp = tid - ul*3;
        int u  = (pu0 + ul) & vmask_out;
        int v  = didx[u*3 + kp];
        const int* svp = spiral + v*12;
        #pragma unroll
        for (int j = 0; j < 12; ++j) gidx[tid*12 + j] = (unsigned short)svp[j];
    }
    __syncthreads();   // also drains the gather loads above (vmcnt ledger reset)

    f32x4 acc[NMT][NNT];
    #pragma unroll
    for (int i = 0; i < NMT; ++i)
        #pragma unroll
        for (int j = 0; j < NNT; ++j) acc[i][j] = (f32x4){0.f, 0.f, 0.f, 0.f};

    const _Float16* xb = x + (size_t)base_in * C_IN;

    // chunk swizzle: slot q of row r holds global chunk q ^ SWZ(r)
    auto SWZ = [](int r) -> int {
        return (CPR == 4) ? ((r & 3) ^ ((r >> 2) & 3)) : (r & 7);
    };

    auto stageA = [&](int g, int buf) {
        const int k0g = g * GS * 32;
        const int sv  = k0g / C_IN;
        const int c0  = k0g % C_IN;                  // halfs
        _Float16* Ad = Ab + (size_t)buf * ASUBH;
        #pragma unroll
        for (int i = 0; i < AIPW; ++i) {
            int t  = (wave*AIPW + i)*64 + lane;
            int r  = t >> CPRS;
            int q  = t & (CPR - 1);
            int qq = q ^ SWZ(r);
            int gr = gidx[r*12 + sv];
            gload_lds16(xb + (size_t)gr*C_IN + c0 + qq*8,
                        Ad + (size_t)(wave*AIPW + i)*512);
        }
        if constexpr (!BREG) {
            _Float16* Bd = Bb + (size_t)buf * BSUBH;
            const _Float16* bs = Wp + ((size_t)(blockIdx.y*NST + g*GS)*4)*BN*8;
            #pragma unroll
            for (int i = 0; i < BIPW; ++i) {
                int t = (wave*BIPW + i)*64 + lane;
                gload_lds16(bs + (size_t)t*8,
                            Bd + (size_t)(wave*BIPW + i)*512);
            }
        }
    };

    if constexpr (BREG) {
        f16x8 b0[GS][NNT], b1[GS][NNT];
        auto loadB = [&](int g, f16x8 (&br)[GS][NNT]) {
            const _Float16* bs = Wp + ((size_t)(blockIdx.y*NST + g*GS)*4)*BN*8;
            #pragma unroll
            for (int sl = 0; sl < GS; ++sl)
                #pragma unroll
                for (int j = 0; j < NNT; ++j) {
                    int n = wn*WTN + j*16 + l16;
                    br[sl][j] = *(const f16x8*)&bs[(size_t)((sl*4 + quad)*BN + n)*8];
                }
        };
        auto computeR = [&](int cb, f16x8 (&br)[GS][NNT]) {
            const _Float16* Ar = Ab + (size_t)cb * ASUBH;
            #pragma unroll
            for (int sl = 0; sl < GS; ++sl) {
                f16x8 af[NMT];
                #pragma unroll
                for (int i = 0; i < NMT; ++i) {
                    int m = wm*WTM + i*16 + l16;
                    af[i] = *(const f16x8*)&Ar[(size_t)(m*CPR + ((sl*4 + quad) ^ SWZ(m)))*8];
                }
                #pragma unroll
                for (int i = 0; i < NMT; ++i)
                    #pragma unroll
                    for (int j = 0; j < NNT; ++j)
                        acc[i][j] = __builtin_amdgcn_mfma_f32_16x16x32_f16(
                            af[i], br[sl][j], acc[i][j], 0, 0, 0);
            }
        };

        stageA(0, 0);
        stageA(1, 1);
        loadB(0, b0);
        int curA = 0;
        auto body = [&](int g, f16x8 (&bUse)[GS][NNT], f16x8 (&bFill)[GS][NNT]) {
            int nx2 = curA + 2; if (nx2 >= 3) nx2 -= 3;
            if (g + 2 < NG) stageA(g + 2, nx2);
            if (g + 1 < NG) loadB(g + 1, bFill);
            __builtin_amdgcn_sched_barrier(0);   // pin loads above the wait
            if (g + 2 < NG)      vm_wait<FULLW>();
            else if (g + 1 < NG) vm_wait<NB>();
            else                 vm_wait<0>();
            __builtin_amdgcn_s_barrier();
            __builtin_amdgcn_sched_barrier(0);
            computeR(curA, bUse);
            asm volatile("s_waitcnt lgkmcnt(0)" ::: "memory");
            __builtin_amdgcn_sched_barrier(0);
            __builtin_amdgcn_s_barrier();
            __builtin_amdgcn_sched_barrier(0);
            curA = (curA + 1 == 3) ? 0 : curA + 1;
        };
        for (int g = 0; g < NG; g += 2) {
            body(g, b0, b1);
            body(g + 1, b1, b0);
        }
    } else {
        auto compute = [&](int cb) {
            const _Float16* Ar = Ab + (size_t)cb * ASUBH;
            const _Float16* Br = Bb + (size_t)cb * BSUBH;
            #pragma unroll
            for (int sl = 0; sl < GS; ++sl) {
                f16x8 af[NMT], bf[NNT];
                #pragma unroll
                for (int i = 0; i < NMT; ++i) {
                    int m = wm*WTM + i*16 + l16;
                    af[i] = *(const f16x8*)&Ar[(size_t)(m*CPR + ((sl*4 + quad) ^ SWZ(m)))*8];
                }
                #pragma unroll
                for (int j = 0; j < NNT; ++j) {
                    int n = wn*WTN + j*16 + l16;
                    bf[j] = *(const f16x8*)&Br[(size_t)((sl*4 + quad)*BN + n)*8];
                }
                #pragma unroll
                for (int i = 0; i < NMT; ++i)
                    #pragma unroll
                    for (int j = 0; j < NNT; ++j)
                        acc[i][j] = __builtin_amdgcn_mfma_f32_16x16x32_f16(
                            af[i], bf[j], acc[i][j], 0, 0, 0);
            }
        };
        if constexpr (NBUF == 3) {
            stageA(0, 0);
            stageA(1, 1);
            int cur = 0;
            for (int g = 0; g < NG; ++g) {
                if (g + 1 < NG) vm_wait<LPW>(); else vm_wait<0>();
                __builtin_amdgcn_s_barrier();
                __builtin_amdgcn_sched_barrier(0);
                int nx2 = cur + 2; if (nx2 >= 3) nx2 -= 3;
                if (g + 2 < NG) stageA(g + 2, nx2);
                compute(cur);
                asm volatile("s_waitcnt lgkmcnt(0)" ::: "memory");
                __builtin_amdgcn_sched_barrier(0);
                __builtin_amdgcn_s_barrier();
                __builtin_amdgcn_sched_barrier(0);
                cur = (cur + 1 == 3) ? 0 : cur + 1;
            }
        } else {
            stageA(0, 0);
            int cur = 0;
            for (int g = 0; g < NG; ++g) {
                if (g + 1 < NG) {
                    stageA(g + 1, cur ^ 1);  // buf cur^1's readers done at g-1 bottom
                    vm_wait<LPW>();          // stage g landed, g+1 stays in flight
                } else {
                    vm_wait<0>();
                }
                __builtin_amdgcn_s_barrier();
                __builtin_amdgcn_sched_barrier(0);
                compute(cur);
                asm volatile("s_waitcnt lgkmcnt(0)" ::: "memory");
                __builtin_amdgcn_sched_barrier(0);
                __builtin_amdgcn_s_barrier();
                __builtin_amdgcn_sched_barrier(0);
                cur ^= 1;
            }
        }
    }

    float bv[NNT];
    #pragma unroll
    for (int j = 0; j < NNT; ++j)
        bv[j] = bias[n0 + wn*WTN + j*16 + l16];

    #pragma unroll
    for (int i = 0; i < NMT; ++i) {
        int row_base = wm*WTM + i*16 + quad*4;
        #pragma unroll
        for (int j = 0; j < NNT; ++j) {
            int col = wn*WTN + j*16 + l16;
            #pragma unroll
            for (int r = 0; r < 4; ++r)
                E[(size_t)(row_base + r)*(BN+4) + col] =
                    (_Float16)elu_f(acc[i][j][r] + bv[j]);
        }
    }
    __syncthreads();

    #pragma unroll
    for (int e = tid; e < P*C4; e += 256) {
        int ul = e / C4;
        int c4 = e - ul*C4;
        int pu = pu0 + ul;
        int u  = pu & vmask_out;
        const float* w = dwt + u*3;
        f16x4 a0 = *(const f16x4*)&E[(size_t)(ul*3 + 0)*(BN+4) + c4*4];
        f16x4 a1 = *(const f16x4*)&E[(size_t)(ul*3 + 1)*(BN+4) + c4*4];
        f16x4 a2 = *(const f16x4*)&E[(size_t)(ul*3 + 2)*(BN+4) + c4*4];
        float ox = w[0]*(float)a0[0] + w[1]*(float)a1[0] + w[2]*(float)a2[0];
        float oy = w[0]*(float)a0[1] + w[1]*(float)a1[1] + w[2]*(float)a2[1];
        float oz = w[0]*(float)a0[2] + w[1]*(float)a1[2] + w[2]*(float)a2[2];
        float ow = w[0]*(float)a0[3] + w[1]*(float)a1[3] + w[2]*(float)a2[3];
        if (OUT_HALF) {
            f16x4 h; h[0]=(_Float16)ox; h[1]=(_Float16)oy; h[2]=(_Float16)oz; h[3]=(_Float16)ow;
            *(f16x4*)&((_Float16*)outv)[(size_t)pu*C_OUT + n0 + c4*4] = h;
        } else {
            float4 o; o.x=ox; o.y=oy; o.z=oz; o.w=ow;
            *(float4*)&((float*)outv)[(size_t)pu*C_OUT + n0 + c4*4] = o;
        }
    }
}

// ---------------- FC1: atomic-free split-K (ks=256, k-chunk 128) ----------------
__global__ __launch_bounds__(256)
void fc1_partial(const float* __restrict__ xflat, const float* __restrict__ Wl1,
                 float* __restrict__ partial)
{
    __shared__ float sb[8704];
    const int tid = threadIdx.x;
    const int n4 = tid & 31;
    const int kq = (tid >> 5) & 3;
    const int mh = tid >> 7;
    const int nt = blockIdx.x;
    const int ks = blockIdx.y;
    const int kbase = ks * 128;

    for (int e = tid; e < 1024; e += 256) {
        int m = e >> 5, k4 = e & 31;
        *(float4*)&sb[m*128 + k4*4] = *(const float4*)&xflat[(size_t)m*32768 + kbase + k4*4];
    }
    __syncthreads();

    float acc[16][4];
    #pragma unroll
    for (int m = 0; m < 16; ++m)
        #pragma unroll
        for (int c = 0; c < 4; ++c) acc[m][c] = 0.0f;

    const float* Wb = Wl1 + (size_t)(kbase + kq*32)*512 + nt*128 + n4*4;
    #pragma unroll 2
    for (int i = 0; i < 32; i += 4) {
        float4 w0 = *(const float4*)(Wb + (size_t)(i+0)*512);
        float4 w1 = *(const float4*)(Wb + (size_t)(i+1)*512);
        float4 w2 = *(const float4*)(Wb + (size_t)(i+2)*512);
        float4 w3 = *(const float4*)(Wb + (size_t)(i+3)*512);
        #pragma unroll
        for (int m = 0; m < 16; ++m) {
            float4 xv = *(const float4*)&sb[(mh*16 + m)*128 + kq*32 + i];
            acc[m][0] += xv.x*w0.x + xv.y*w1.x + xv.z*w2.x + xv.w*w3.x;
            acc[m][1] += xv.x*w0.y + xv.y*w1.y + xv.z*w2.y + xv.w*w3.y;
            acc[m][2] += xv.x*w0.z + xv.y*w1.z + xv.z*w2.z + xv.w*w3.z;
            acc[m][3] += xv.x*w0.w + xv.y*w1.w + xv.z*w2.w + xv.w*w3.w;
        }
    }
    __syncthreads();

    int slot = (mh*2 + (kq >> 1))*32 + n4;
    if (kq & 1) {
        #pragma unroll
        for (int m = 0; m < 16; ++m)
            *(float4*)&sb[slot*68 + m*4] = *(float4*)&acc[m][0];
    }
    __syncthreads();
    if (!(kq & 1)) {
        #pragma unroll
        for (int m = 0; m < 16; ++m) {
            float4 v = *(const float4*)&sb[slot*68 + m*4];
            acc[m][0] += v.x; acc[m][1] += v.y; acc[m][2] += v.z; acc[m][3] += v.w;
        }
    }
    __syncthreads();
    int slot2 = mh*32 + n4;
    if (kq == 2) {
        #pragma unroll
        for (int m = 0; m < 16; ++m)
            *(float4*)&sb[slot2*68 + m*4] = *(float4*)&acc[m][0];
    }
    __syncthreads();
    if (kq == 0) {
        float* pb = partial + ((size_t)(ks*4 + nt)*32 + mh*16)*128 + n4*4;
        #pragma unroll
        for (int m = 0; m < 16; ++m) {
            float4 v = *(const float4*)&sb[slot2*68 + m*4];
            float4 o;
            o.x = acc[m][0] + v.x; o.y = acc[m][1] + v.y;
            o.z = acc[m][2] + v.z; o.w = acc[m][3] + v.w;
            *(float4*)(pb + (size_t)m*128) = o;
        }
    }
}

// ---------------- FC1 reduce + ELU + FC2, fused (one block per batch row m) ----------------
__global__ __launch_bounds__(512)
void fc1_finish(const float* __restrict__ partial, const float* __restrict__ bl1,
                const float* __restrict__ Wl2, const float* __restrict__ bl2,
                float* __restrict__ out)
{
    __shared__ float hh[512];
    __shared__ float ps[512];
    const int m = blockIdx.x;
    const int tid = threadIdx.x;
    const int nt = tid >> 7, nl = tid & 127;

    const float* p = partial + ((size_t)nt*32 + m)*128 + nl;
    float s = 0.0f;
    #pragma unroll 8
    for (int ks = 0; ks < 256; ++ks)
        s += p[(size_t)ks*16384];
    float h = elu_f(s + bl1[tid]);
    out[(size_t)m*512 + tid] = h;      // hout output
    hh[tid] = h;
    __syncthreads();

    // fc2: y[m][c] = bl2[c] + sum_k hh[k]*Wl2[k*64+c]
    const int c  = tid & 63;
    const int kc = tid >> 6;
    float a = 0.0f;
    #pragma unroll 8
    for (int k = kc*64; k < kc*64 + 64; ++k)
        a += hh[k] * Wl2[(size_t)k*64 + c];
    ps[tid] = a;
    __syncthreads();
    if (tid < 64) {
        float y = bl2[tid];
        #pragma unroll
        for (int j = 0; j < 8; ++j) y += ps[j*64 + tid];
        out[16384 + (size_t)m*64 + tid] = y;
    }
}

extern "C" void kernel_launch(void* const* d_in, const int* in_sizes, int n_in,
                              void* d_out, int out_size, void* d_ws, size_t ws_size,
                              hipStream_t stream)
{
    (void)in_sizes; (void)n_in; (void)out_size; (void)ws_size;

    const float* x0 = (const float*)d_in[0];
    const int*   sp[4]; const int* didx[4]; const float* dwp[4];
    const float* Wp[4]; const float* bp[4];
    for (int i = 0; i < 4; ++i) {
        sp[i]   = (const int*)  d_in[1 + i*5 + 0];
        didx[i] = (const int*)  d_in[1 + i*5 + 1];
        dwp[i]  = (const float*)d_in[1 + i*5 + 2];
        Wp[i]   = (const float*)d_in[1 + i*5 + 3];
        bp[i]   = (const float*)d_in[1 + i*5 + 4];
    }
    const float* Wl1 = (const float*)d_in[21];
    const float* bl1 = (const float*)d_in[22];
    const float* Wl2 = (const float*)d_in[23];
    const float* bl2 = (const float*)d_in[24];
    float* out = (float*)d_out;

    char* wsb = (char*)d_ws;
    float* persist      = (float*)wsb;                    // 4 MB   (32,128,256) fp32
    float* partial      = (float*)(wsb + (4<<20));        // 16.8 MB (1024 x 4096 f32)
    _Float16* xT        = (_Float16*)(wsb + (24<<20));    // 8 MB   (2 halves x 4 MB)
    _Float16* pooled0   = (_Float16*)(wsb + (32<<20));    // 16 MB  (32,8192,32) fp16
    _Float16* pooled1   = (_Float16*)(wsb + (48<<20));    // 8 MB   (32,2048,64) fp16
    _Float16* pooled2   = (_Float16*)(wsb + (56<<20));    // 4 MB   (32,512,128) fp16
    unsigned int* gidx0 = (unsigned int*)(wsb + (60<<20));// 0.75 MB
    _Float16* w0h       = (_Float16*)(wsb + (61<<20));
    _Float16* w1h       = w0h + 2048;
    _Float16* w2h       = w1h + 24576;
    _Float16* w3h       = w2h + 98304;

    // setup: x transpose + all weight/index prep in ONE dispatch
    setup_all<<<3816, 256, 0, stream>>>(x0, xT,
                                        Wp[0], Wp[1], Wp[2], Wp[3],
                                        didx[0], sp[0],
                                        w0h, w1h, w2h, w3h, gidx0);

    // L0: conv0 (both halves, 1 dispatch)
    conv0T<<<2048, 256, 0, stream>>>(xT, gidx0, w0h, bp[0], dwp[0], pooled0);

    // L1: conv(32->64, K=384) + pool -> fp16 (32, 2048, 64)
    //     NBUF=2 counted, B in LDS (proven path; 37.4KB -> 4 blocks/CU)
    conv_pool_mfma<32,64,64,64,4,1,true,2,false><<<1024, 256, 0, stream>>>(
        pooled0, sp[1], w1h, bp[1], didx[1], dwp[1], pooled1, 13, 11, 2);

    // L2: conv(64->128, K=768) + pool -> fp16 (32, 512, 128)
    //     BREG: A-only LDS (38.3KB -> 4 blocks/CU), B double-buffered in regs
    conv_pool_mfma<64,128,32,64,2,2,true,3,true><<<dim3(512, 2), 256, 0, stream>>>(
        pooled1, sp[2], w2h, bp[2], didx[2], dwp[2], pooled2, 11, 9, 2);

    // L3: conv(128->256, K=1536) + pool -> fp32 persist (32, 128, 256) [BREG]
    conv_pool_mfma<128,256,32,64,2,2,false,3,true><<<dim3(128, 4), 256, 0, stream>>>(
        pooled2, sp[3], w3h, bp[3], didx[3], dwp[3], persist, 9, 7, 2);

    // FC1: (32,32768)@(32768,512), split-K partials then fused reduce+ELU+FC2
    fc1_partial<<<dim3(4, 256), 256, 0, stream>>>(persist, Wl1, partial);
    fc1_finish<<<32, 512, 0, stream>>>(partial, bl1, Wl2, bl2, out);
}